// Round 6
// baseline (772.326 us; speedup 1.0000x reference)
//
#include <hip/hip_runtime.h>

typedef unsigned short u16;
typedef unsigned int u32;
typedef short short8 __attribute__((ext_vector_type(8)));
typedef float f32x4 __attribute__((ext_vector_type(4)));

#define DEV static __device__ __forceinline__

DEV float bf2f(u16 v) { return __uint_as_float((u32)v << 16); }
DEV u16 f2bf(float f) {
    u32 x = __float_as_uint(f);
    return (u16)((x + 0x7fffu + ((x >> 16) & 1u)) >> 16);  // RNE
}

constexpr int Bn = 8, Tn = 2048, Fn = 80, NF = 64;
constexpr int H1 = 1024, W1n = 40;          // after conv0 (stride 2)
constexpr int Sn = 512,  W2n = 20;          // after conv1 (stride 2)
constexpr int PK = 1280;                    // 20*64
constexpr int I0 = 96;                      // 32 capsules * window 3
constexpr int IH = 48;                      // i-split: 48 per thread-group
constexpr int O0 = 32;                      // conv capsules
constexpr int O1 = 31;                      // class capsules
constexpr int CP = 97;                      // cct row stride (conflict-free)
constexpr int NW0 = I0 * O0 * 8 * 8;        // 196608
constexpr int NW1 = I0 * O1 * 8 * 8;        // 190464
constexpr int KC1 = 576;                    // conv1 GEMM K (9*64)

// ---------------------------------------------------------------- DPP helpers
template <int CTRL>
DEV float dpp_mov(float x) {
    return __int_as_float(__builtin_amdgcn_update_dpp(
        0, __float_as_int(x), CTRL, 0xF, 0xF, true));
}
DEV float sum8(float x) {
    x += dpp_mov<0xB1>(x);    // quad_perm xor1
    x += dpp_mov<0x4E>(x);    // quad_perm xor2
    x += dpp_mov<0x141>(x);   // row_half_mirror
    return x;
}

// ---------------------------------------------------------------- block reduce (up to 8 waves)
DEV float2 block_sum2w(float a, float b, int tid, int nwave, float* lds /*>=16*/) {
    #pragma unroll
    for (int m = 1; m < 64; m <<= 1) {
        a += __shfl_xor(a, m);
        b += __shfl_xor(b, m);
    }
    int wid = tid >> 6;
    __syncthreads();
    if ((tid & 63) == 0) { lds[wid] = a; lds[8 + wid] = b; }
    __syncthreads();
    float ra = 0.f, rb = 0.f;
    for (int w = 0; w < nwave; ++w) { ra += lds[w]; rb += lds[8 + w]; }
    return make_float2(ra, rb);
}

// ---------------------------------------------------------------- K0: prep
__global__ void __launch_bounds__(256) k_prep(
        const float* __restrict__ w0, const float* __restrict__ w1c,
        const float* __restrict__ cw1, const float* __restrict__ cb1,
        const float* __restrict__ cw2, const float* __restrict__ cb2,
        u16* __restrict__ w0b, u16* __restrict__ w1b,
        u16* __restrict__ wt, float* __restrict__ biasi) {
    int idx = blockIdx.x * 256 + threadIdx.x;
    if (idx < NW0) w0b[idx] = f2bf(w0[idx]);
    if (idx < NW1) w1b[idx] = f2bf(w1c[idx]);
    if (idx < 128 * KC1) {
        int n = idx / KC1, k = idx - n * KC1;
        int c = n >> 1, s = n & 1;
        const float* w = s ? cw2 : cw1;   // [3,3,64,64] flat: k*64 + c
        wt[idx] = f2bf(w[k * 64 + c]);
    }
    if (idx < 128) {
        int c = idx >> 1, s = idx & 1;
        biasi[idx] = (s ? cb2 : cb1)[c];
    }
}

// ---------------------------------------------------------------- K1: conv0 maxout
__global__ void __launch_bounds__(256) k_conv0(
        const float* __restrict__ in,
        const float* __restrict__ w1, const float* __restrict__ b1,
        const float* __restrict__ w2, const float* __restrict__ b2,
        const int* __restrict__ lens, u16* __restrict__ x1) {
    int idx = blockIdx.x * 256 + threadIdx.x;
    if (idx >= Bn * H1 * W1n * NF) return;
    int c = idx & 63;
    int rest = idx >> 6;
    int w = rest % W1n; rest /= W1n;
    int h = rest % H1;
    int b = rest / H1;
    float out = 0.f;
    int vl2 = (lens[b] + 1) >> 1;
    if (h < vl2) {
        float a1 = b1[c], a2 = b2[c];
        #pragma unroll
        for (int r = 0; r < 3; ++r) {
            int t = 2 * h + r;
            if (t < Tn) {
                #pragma unroll
                for (int q = 0; q < 3; ++q) {
                    int f = 2 * w + q;
                    if (f < Fn) {
                        float v = in[(b * Tn + t) * Fn + f];
                        int wi = (r * 3 + q) * 64 + c;
                        a1 = fmaf(v, w1[wi], a1);
                        a2 = fmaf(v, w2[wi], a2);
                    }
                }
            }
        }
        out = fmaxf(a1, a2);
    }
    x1[idx] = f2bf(out);
}

// ---------------------------------------------------------------- K2: conv1 via MFMA implicit GEMM
__global__ void __launch_bounds__(256) k_conv1(
        const u16* __restrict__ x1, const u16* __restrict__ wt,
        const float* __restrict__ biasi, const int* __restrict__ lens,
        u16* __restrict__ x2) {
    constexpr int LD = 40;
    __shared__ u16 Al[2][128 * LD];
    __shared__ u16 Bl[2][128 * LD];
    __shared__ float bs_lds[128];

    int tid = threadIdx.x;
    int m0 = blockIdx.x * 128;
    int b = m0 / 10240;
    int vl4 = (lens[b] + 3) >> 2;

    if (tid < 128) bs_lds[tid] = biasi[tid];

    int srow = tid >> 1;
    int shalf = tid & 1;
    int am = m0 + srow;
    int aw = am % 20;
    int ah = (am / 20) % 512;
    const u16* abase = x1 + (((size_t)b * 1024 + 2 * ah) * 40 + 2 * aw) * 64;
    const u16* bbase = wt + srow * KC1;

    const uint4 uz = make_uint4(0, 0, 0, 0);
    uint4 na0, na1, nb0, nb1;
    {
        const u16* ap = abase + shalf * 16;
        na0 = *(const uint4*)(ap);
        na1 = *(const uint4*)(ap + 8);
        const u16* bp = bbase + shalf * 16;
        nb0 = *(const uint4*)(bp);
        nb1 = *(const uint4*)(bp + 8);
    }
    {
        u16* awp = &Al[0][srow * LD + shalf * 16];
        *(uint4*)awp = na0; *(uint4*)(awp + 8) = na1;
        u16* bwp = &Bl[0][srow * LD + shalf * 16];
        *(uint4*)bwp = nb0; *(uint4*)(bwp + 8) = nb1;
    }
    __syncthreads();

    int lane = tid & 63;
    int wid = tid >> 6;
    int mw = wid & 1, nw = wid >> 1;
    int frow = lane & 15;
    int koff = (lane >> 4) * 8;

    f32x4 acc[4][4] = {};
    int buf = 0;

    #pragma unroll
    for (int kc = 0; kc < 18; ++kc) {
        if (kc < 17) {
            int kn = kc + 1;
            int rq = kn >> 1, ci0 = (kn & 1) * 32;
            int r = rq / 3, q = rq - 3 * r;
            bool v = (2 * ah + r < 1024) && (2 * aw + q < 40);
            const u16* ap = abase + (r * 40 + q) * 64 + ci0 + shalf * 16;
            na0 = v ? *(const uint4*)(ap) : uz;
            na1 = v ? *(const uint4*)(ap + 8) : uz;
            const u16* bp = bbase + kn * 32 + shalf * 16;
            nb0 = *(const uint4*)(bp);
            nb1 = *(const uint4*)(bp + 8);
        }
        const u16* Ar = &Al[buf][(mw * 64 + frow) * LD + koff];
        const u16* Br = &Bl[buf][(nw * 64 + frow) * LD + koff];
        short8 af[4], bfr[4];
        #pragma unroll
        for (int s = 0; s < 4; ++s) {
            af[s]  = *(const short8*)(Ar + s * 16 * LD);
            bfr[s] = *(const short8*)(Br + s * 16 * LD);
        }
        #pragma unroll
        for (int sm = 0; sm < 4; ++sm)
            #pragma unroll
            for (int sn = 0; sn < 4; ++sn)
                acc[sm][sn] = __builtin_amdgcn_mfma_f32_16x16x32_bf16(
                    af[sm], bfr[sn], acc[sm][sn], 0, 0, 0);
        if (kc < 17) {
            buf ^= 1;
            u16* awp = &Al[buf][srow * LD + shalf * 16];
            *(uint4*)awp = na0; *(uint4*)(awp + 8) = na1;
            u16* bwp = &Bl[buf][srow * LD + shalf * 16];
            *(uint4*)bwp = nb0; *(uint4*)(bwp + 8) = nb1;
            __syncthreads();
        }
    }

    int orow = (lane >> 4) * 4;
    int ncol = lane & 15;
    #pragma unroll
    for (int sm = 0; sm < 4; ++sm) {
        #pragma unroll
        for (int sn = 0; sn < 4; ++sn) {
            int np = nw * 64 + sn * 16 + ncol;
            float bia = bs_lds[np];
            #pragma unroll
            for (int r = 0; r < 4; ++r) {
                float v = acc[sm][sn][r] + bia;
                float o = fmaxf(v, dpp_mov<0xB1>(v));
                if (!(lane & 1)) {
                    int gm = m0 + mw * 64 + sm * 16 + orow + r;
                    int w = gm % 20;
                    int h = (gm / 20) % 512;
                    float res = (h >= vl4) ? 0.f : o;
                    x2[((size_t)(b * 512 + h) * 20 + w) * 64 + (np >> 1)] = f2bf(res);
                }
            }
        }
    }
}

// ---------------------------------------------------------------- K3a: projection
__global__ void __launch_bounds__(256) k_proj(
        const u16* __restrict__ x2, const float* __restrict__ pw,
        const float* __restrict__ pb, float* __restrict__ proj) {
    int bs = blockIdx.x;
    int tid = threadIdx.x;
    int o = tid & 31, part = tid >> 5;
    const u16* row = &x2[(size_t)bs * PK];
    float acc = 0.f;
    int k0 = part * 160;
    #pragma unroll 8
    for (int k = 0; k < 160; ++k)
        acc = fmaf(bf2f(row[k0 + k]), pw[(k0 + k) * 32 + o], acc);
    __shared__ float red[256];
    red[tid] = acc;
    __syncthreads();
    if (tid < 32) {
        float s = 0.f;
        #pragma unroll
        for (int p = 0; p < 8; ++p) s += red[p * 32 + tid];
        proj[bs * 32 + tid] = s + pb[tid];
    }
}

// ---------------------------------------------------------------- K3b: enc conv + mask + squash + LN
__global__ void __launch_bounds__(256) k_enc(
        const float* __restrict__ proj,
        const float* __restrict__ ew1, const float* __restrict__ eb1,
        const float* __restrict__ ew2, const float* __restrict__ eb2,
        const int* __restrict__ lens, float* __restrict__ emb0) {
    int bs = blockIdx.x;
    int s = bs & (Sn - 1);
    int b = bs >> 9;
    int tid = threadIdx.x;
    __shared__ float rows[3][32];
    __shared__ float red[16];
    if (tid < 96) {
        int r = tid >> 5, n = tid & 31;
        int sr = s - 1 + r;
        rows[r][n] = (sr >= 0 && sr < Sn) ? proj[(b * Sn + sr) * 32 + n] : 0.f;
    }
    __syncthreads();

    int n = tid >> 3, d = tid & 7;
    float a1 = eb1[d], a2 = eb2[d];
    #pragma unroll
    for (int r = 0; r < 3; ++r) {
        #pragma unroll
        for (int q = 0; q < 3; ++q) {
            int nn = n - 1 + q;
            if (nn >= 0 && nn < 32) {
                float v = rows[r][nn];
                int wi = (r * 3 + q) * 8 + d;
                a1 = fmaf(v, ew1[wi], a1);
                a2 = fmaf(v, ew2[wi], a2);
            }
        }
    }
    float x = fmaxf(a1, a2);
    int vl4 = (lens[b] + 3) >> 2;
    if (s >= vl4) x = 0.f;

    float sq = sum8(x * x);
    x = x * (sq / (1.f + sq) * rsqrtf(sq + 1e-6f));

    float2 ss = block_sum2w(x, x * x, tid, 4, red);
    float mu = ss.x * (1.f / 256.f);
    float var = ss.y * (1.f / 256.f) - mu * mu;
    emb0[bs * 256 + tid] = (x - mu) * rsqrtf(var + 1e-3f);
}

// ---------------------------------------------------------------- K4: caps layer 0 (512 thr, i-split)
__global__ void __launch_bounds__(512, 1) k_caps0(
        const float* __restrict__ embin, const u16* __restrict__ W0,
        const float* __restrict__ B0, float* __restrict__ embout) {
    int bs = blockIdx.x;
    int s = bs & (Sn - 1);
    int b = bs >> 9;
    int tid = threadIdx.x;
    int od = tid & 255;
    int o = od >> 3;
    int g = tid >> 8;                 // i-group: 0 -> i<48, 1 -> i>=48
    int i0 = g * IH;

    __shared__ __align__(16) float win[I0 * 8];
    __shared__ float blog[I0 * 33];
    __shared__ float cct[O0 * CP];
    __shared__ float part[512];
    __shared__ float red[16];

    for (int i = tid; i < I0 * 8; i += 512) {
        int wj = i >> 8;
        int sr = s + wj - 1;
        win[i] = (sr >= 0 && sr < Sn) ? embin[(b * Sn + sr) * 256 + (i & 255)] : 0.f;
    }
    for (int i = tid; i < I0 * 33; i += 512) blog[i] = 0.f;
    __syncthreads();

    float u_reg[IH];
    {
        const uint4* Wv = (const uint4*)W0;
        const float4* w4 = (const float4*)win;
        #pragma unroll
        for (int ii = 0; ii < IH; ++ii) {
            int i = i0 + ii;
            uint4 wv = Wv[i * 256 + od];
            float4 wa = w4[i * 2], wb = w4[i * 2 + 1];
            float acc = B0[i * 256 + od];
            acc = fmaf(__uint_as_float(wv.x << 16),         wa.x, acc);
            acc = fmaf(__uint_as_float(wv.x & 0xffff0000u), wa.y, acc);
            acc = fmaf(__uint_as_float(wv.y << 16),         wa.z, acc);
            acc = fmaf(__uint_as_float(wv.y & 0xffff0000u), wa.w, acc);
            acc = fmaf(__uint_as_float(wv.z << 16),         wb.x, acc);
            acc = fmaf(__uint_as_float(wv.z & 0xffff0000u), wb.y, acc);
            acc = fmaf(__uint_as_float(wv.w << 16),         wb.z, acc);
            acc = fmaf(__uint_as_float(wv.w & 0xffff0000u), wb.w, acc);
            u_reg[ii] = acc;
        }
    }

    float vval = 0.f;
    for (int it = 0; it < 3; ++it) {
        if (tid < I0) {
            float m = -1e30f;
            for (int oo = 0; oo < O0; ++oo) m = fmaxf(m, blog[tid * 33 + oo]);
            float ssum = 0.f;
            for (int oo = 0; oo < O0; ++oo) ssum += __expf(blog[tid * 33 + oo] - m);
            float inv = __builtin_amdgcn_rcpf(ssum);
            for (int oo = 0; oo < O0; ++oo)
                cct[oo * CP + tid] = __expf(blog[tid * 33 + oo] - m) * inv;
        }
        __syncthreads();
        float svp = 0.f;
        {
            const float* cr = &cct[o * CP + i0];
            #pragma unroll
            for (int ii = 0; ii < IH; ++ii) svp = fmaf(cr[ii], u_reg[ii], svp);
        }
        part[tid] = svp;
        __syncthreads();
        float sv = part[od] + part[256 + od];
        float sq = sum8(sv * sv);
        vval = sv * (sq / (1.f + sq) * rsqrtf(sq + 1e-6f));
        if (it < 2) {
            #pragma unroll
            for (int ii = 0; ii < IH; ++ii) {
                float p = sum8(u_reg[ii] * vval);
                if ((tid & 7) == 0) blog[(i0 + ii) * 33 + o] += p;
            }
            __syncthreads();
        }
    }

    // layernorm over 256 (each value duplicated across g -> normalize by 512)
    float2 ss = block_sum2w(vval, vval * vval, tid, 8, red);
    float mu = ss.x * (1.f / 512.f);
    float var = ss.y * (1.f / 512.f) - mu * mu;
    if (g == 0)
        embout[bs * 256 + od] = (vval - mu) * rsqrtf(var + 1e-3f);
}

// ---------------------------------------------------------------- K5: caps layer 1 + epilogue (512 thr)
__global__ void __launch_bounds__(512, 1) k_caps1(
        const float* __restrict__ embin, const u16* __restrict__ W1,
        const float* __restrict__ B1, float* __restrict__ outp) {
    int bs = blockIdx.x;
    int s = bs & (Sn - 1);
    int b = bs >> 9;
    int tid = threadIdx.x;
    int od = tid & 255;
    int o = od >> 3, d = od & 7;
    int g = tid >> 8;
    int i0 = g * IH;
    bool valid = (o < O1);
    int oc = valid ? o : (O1 - 1);
    int ocd = oc * 8 + d;

    __shared__ __align__(16) float win[I0 * 8];
    __shared__ float blog[I0 * 33];
    __shared__ float cct[O1 * CP];
    __shared__ float part[512];
    __shared__ float red[16];
    __shared__ float lenb[O1];
    __shared__ float mv2[2];

    for (int i = tid; i < I0 * 8; i += 512) {
        int wj = i >> 8;
        int sr = s + wj - 1;
        win[i] = (sr >= 0 && sr < Sn) ? embin[(b * Sn + sr) * 256 + (i & 255)] : 0.f;
    }
    for (int i = tid; i < I0 * 33; i += 512) blog[i] = 0.f;
    __syncthreads();

    float u_reg[IH];
    {
        const uint4* Wv = (const uint4*)W1;
        const float4* w4 = (const float4*)win;
        #pragma unroll
        for (int ii = 0; ii < IH; ++ii) {
            int i = i0 + ii;
            uint4 wv = Wv[i * 248 + ocd];
            float4 wa = w4[i * 2], wb = w4[i * 2 + 1];
            float acc = B1[i * 248 + ocd];
            acc = fmaf(__uint_as_float(wv.x << 16),         wa.x, acc);
            acc = fmaf(__uint_as_float(wv.x & 0xffff0000u), wa.y, acc);
            acc = fmaf(__uint_as_float(wv.y << 16),         wa.z, acc);
            acc = fmaf(__uint_as_float(wv.y & 0xffff0000u), wa.w, acc);
            acc = fmaf(__uint_as_float(wv.z << 16),         wb.x, acc);
            acc = fmaf(__uint_as_float(wv.z & 0xffff0000u), wb.y, acc);
            acc = fmaf(__uint_as_float(wv.w << 16),         wb.z, acc);
            acc = fmaf(__uint_as_float(wv.w & 0xffff0000u), wb.w, acc);
            u_reg[ii] = acc;
        }
    }

    float vval = 0.f;
    for (int it = 0; it < 3; ++it) {
        if (tid < I0) {
            float m = -1e30f;
            for (int oo = 0; oo < O1; ++oo) {
                float lv = blog[tid * 33 + oo] + (oo == 0 ? -1e9f : 0.f);
                m = fmaxf(m, lv);
            }
            float ssum = 0.f;
            for (int oo = 0; oo < O1; ++oo) {
                float lv = blog[tid * 33 + oo] + (oo == 0 ? -1e9f : 0.f);
                ssum += __expf(lv - m);
            }
            float inv = __builtin_amdgcn_rcpf(ssum);
            for (int oo = 0; oo < O1; ++oo) {
                float lv = blog[tid * 33 + oo] + (oo == 0 ? -1e9f : 0.f);
                cct[oo * CP + tid] = __expf(lv - m) * inv;
            }
        }
        __syncthreads();
        float svp = 0.f;
        {
            const float* cr = &cct[oc * CP + i0];
            #pragma unroll
            for (int ii = 0; ii < IH; ++ii) svp = fmaf(cr[ii], u_reg[ii], svp);
        }
        part[tid] = svp;
        __syncthreads();
        float sv = part[od] + part[256 + od];
        float sq = sum8(sv * sv);
        vval = sv * (sq / (1.f + sq) * rsqrtf(sq + 1e-6f));
        if (!valid) vval = 0.f;
        if (it < 2) {
            #pragma unroll
            for (int ii = 0; ii < IH; ++ii) {
                float p = sum8(u_reg[ii] * vval);
                if ((tid & 7) == 0 && valid) blog[(i0 + ii) * 33 + o] += p;
            }
            __syncthreads();
        }
    }

    // layernorm over 248 (duplicated across g -> normalize by 496)
    float2 ss = block_sum2w(vval, vval * vval, tid, 8, red);
    float mu = ss.x * (1.f / 496.f);
    float var = ss.y * (1.f / 496.f) - mu * mu;
    float y = (vval - mu) * rsqrtf(var + 1e-3f);

    float sq = sum8(y * y);
    if (g == 0 && valid && (od & 7) == 0) lenb[o] = sqrtf(sq + 1e-6f);
    __syncthreads();

    if (tid == 0) {
        float s1 = 0.f, s2 = 0.f;
        for (int oo = 0; oo < O1; ++oo) { float t = lenb[oo]; s1 += t; s2 += t * t; }
        float m2 = s1 / 31.f;
        mv2[0] = m2;
        mv2[1] = rsqrtf(s2 / 31.f - m2 * m2 + 1e-3f);
    }
    __syncthreads();
    if (tid < O1)
        outp[(size_t)bs * O1 + tid] = (lenb[tid] - mv2[0]) * mv2[1];
}

// ---------------------------------------------------------------- launch
extern "C" void kernel_launch(void* const* d_in, const int* in_sizes, int n_in,
                              void* d_out, int out_size, void* d_ws, size_t ws_size,
                              hipStream_t stream) {
    const float* inputs = (const float*)d_in[0];
    const float* c0w1 = (const float*)d_in[1];
    const float* c0b1 = (const float*)d_in[2];
    const float* c0w2 = (const float*)d_in[3];
    const float* c0b2 = (const float*)d_in[4];
    const float* c1w1 = (const float*)d_in[5];
    const float* c1b1 = (const float*)d_in[6];
    const float* c1w2 = (const float*)d_in[7];
    const float* c1b2 = (const float*)d_in[8];
    const float* pw   = (const float*)d_in[9];
    const float* pb   = (const float*)d_in[10];
    const float* ew1  = (const float*)d_in[11];
    const float* eb1  = (const float*)d_in[12];
    const float* ew2  = (const float*)d_in[13];
    const float* eb2  = (const float*)d_in[14];
    const float* W0   = (const float*)d_in[15];
    const float* B0   = (const float*)d_in[16];
    const float* W1   = (const float*)d_in[17];
    const float* B1   = (const float*)d_in[18];
    const int* lens = (const int*)d_in[19];

    char* ws = (char*)d_ws;
    u16*   x1    = (u16*)(ws);                       // 41,943,040 B
    u16*   x2    = (u16*)(ws + 41943040);            // 10,485,760 B (bf16)
    float* proj  = (float*)(ws + 52428800);          //    524,288 B
    float* emb0  = (float*)(ws + 52953088);          //  4,194,304 B
    float* emb1  = (float*)(ws + 57147392);          //  4,194,304 B
    u16*   W0b   = (u16*)(ws + 61341696);            //    393,216 B
    u16*   W1b   = (u16*)(ws + 61734912);            //    380,928 B
    u16*   wt    = (u16*)(ws + 62115840);            //    147,456 B
    float* biasi = (float*)(ws + 62263296);          //        512 B (end ~62.3 MB)

    k_prep<<<(NW0 + 255) / 256, 256, 0, stream>>>(
        W0, W1, c1w1, c1b1, c1w2, c1b2, W0b, W1b, wt, biasi);
    k_conv0<<<(Bn * H1 * W1n * NF) / 256, 256, 0, stream>>>(
        inputs, c0w1, c0b1, c0w2, c0b2, lens, x1);
    k_conv1<<<640, 256, 0, stream>>>(x1, wt, biasi, lens, x2);
    k_proj<<<Bn * Sn, 256, 0, stream>>>(x2, pw, pb, proj);
    k_enc<<<Bn * Sn, 256, 0, stream>>>(proj, ew1, eb1, ew2, eb2, lens, emb0);
    k_caps0<<<Bn * Sn, 512, 0, stream>>>(emb0, W0b, B0, emb1);
    k_caps1<<<Bn * Sn, 512, 0, stream>>>(emb1, W1b, B1, (float*)d_out);
}

// Round 7
// 505.733 us; speedup vs baseline: 1.5271x; 1.5271x over previous
//
#include <hip/hip_runtime.h>

typedef unsigned short u16;
typedef unsigned int u32;
typedef short short8 __attribute__((ext_vector_type(8)));
typedef float f32x4 __attribute__((ext_vector_type(4)));
typedef _Float16 h2 __attribute__((ext_vector_type(2)));

#define DEV static __device__ __forceinline__

DEV float bf2f(u16 v) { return __uint_as_float((u32)v << 16); }
DEV u16 f2bf(float f) {
    u32 x = __float_as_uint(f);
    return (u16)((x + 0x7fffu + ((x >> 16) & 1u)) >> 16);  // RNE
}
DEV u16 f2h(float f) {
    union { _Float16 h; u16 u; } c; c.h = (_Float16)f; return c.u;
}
DEV u32 pack2h(float a, float b) {
    union { u32 u; _Float16 h[2]; } c;
    c.h[0] = (_Float16)a; c.h[1] = (_Float16)b; return c.u;
}
DEV h2 u2h(u32 x) { union { u32 u; h2 h; } c; c.u = x; return c.h; }

#if __has_builtin(__builtin_amdgcn_fdot2)
DEV float dot2(u32 a, u32 b, float c) {
    return __builtin_amdgcn_fdot2(u2h(a), u2h(b), c, false);
}
#else
DEV float dot2(u32 a, u32 b, float c) {
    h2 ha = u2h(a), hb = u2h(b);
    c = fmaf((float)ha[0], (float)hb[0], c);
    return fmaf((float)ha[1], (float)hb[1], c);
}
#endif

constexpr int Bn = 8, Tn = 2048, Fn = 80, NF = 64;
constexpr int H1 = 1024, W1n = 40;          // after conv0 (stride 2)
constexpr int Sn = 512,  W2n = 20;          // after conv1 (stride 2)
constexpr int PK = 1280;                    // 20*64
constexpr int I0 = 96;                      // 32 capsules * window 3
constexpr int O0 = 32;                      // conv capsules
constexpr int O1 = 31;                      // class capsules
constexpr int CP = 97;                      // cct row stride (conflict-free)
constexpr int NW0 = I0 * O0 * 8 * 8;        // 196608
constexpr int NW1 = I0 * O1 * 8 * 8;        // 190464
constexpr int KC1 = 576;                    // conv1 GEMM K (9*64)

// ---------------------------------------------------------------- DPP helpers
template <int CTRL>
DEV float dpp_mov(float x) {
    return __int_as_float(__builtin_amdgcn_update_dpp(
        0, __float_as_int(x), CTRL, 0xF, 0xF, true));
}
DEV float sum8(float x) {
    x += dpp_mov<0xB1>(x);    // quad_perm xor1
    x += dpp_mov<0x4E>(x);    // quad_perm xor2
    x += dpp_mov<0x141>(x);   // row_half_mirror
    return x;
}

// ---------------------------------------------------------------- block reduce (4 waves)
DEV float2 block_sum2(float a, float b, int tid, float* lds /*>=8 floats*/) {
    #pragma unroll
    for (int m = 1; m < 64; m <<= 1) {
        a += __shfl_xor(a, m);
        b += __shfl_xor(b, m);
    }
    int wid = tid >> 6;
    __syncthreads();
    if ((tid & 63) == 0) { lds[wid * 2] = a; lds[wid * 2 + 1] = b; }
    __syncthreads();
    float ra = lds[0] + lds[2] + lds[4] + lds[6];
    float rb = lds[1] + lds[3] + lds[5] + lds[7];
    return make_float2(ra, rb);
}

// ---------------------------------------------------------------- K0: prep
// caps W -> f16; conv1 weights -> wt[n'=2c+s][k] bf16 (+ interleaved bias)
__global__ void __launch_bounds__(256) k_prep(
        const float* __restrict__ w0, const float* __restrict__ w1c,
        const float* __restrict__ cw1, const float* __restrict__ cb1,
        const float* __restrict__ cw2, const float* __restrict__ cb2,
        u16* __restrict__ w0h, u16* __restrict__ w1h,
        u16* __restrict__ wt, float* __restrict__ biasi) {
    int idx = blockIdx.x * 256 + threadIdx.x;
    if (idx < NW0) w0h[idx] = f2h(w0[idx]);
    if (idx < NW1) w1h[idx] = f2h(w1c[idx]);
    if (idx < 128 * KC1) {
        int n = idx / KC1, k = idx - n * KC1;
        int c = n >> 1, s = n & 1;
        const float* w = s ? cw2 : cw1;   // [3,3,64,64] flat: k*64 + c
        wt[idx] = f2bf(w[k * 64 + c]);
    }
    if (idx < 128) {
        int c = idx >> 1, s = idx & 1;
        biasi[idx] = (s ? cb2 : cb1)[c];
    }
}

// ---------------------------------------------------------------- K1: conv0 maxout
__global__ void __launch_bounds__(256) k_conv0(
        const float* __restrict__ in,
        const float* __restrict__ w1, const float* __restrict__ b1,
        const float* __restrict__ w2, const float* __restrict__ b2,
        const int* __restrict__ lens, u16* __restrict__ x1) {
    int idx = blockIdx.x * 256 + threadIdx.x;
    if (idx >= Bn * H1 * W1n * NF) return;
    int c = idx & 63;
    int rest = idx >> 6;
    int w = rest % W1n; rest /= W1n;
    int h = rest % H1;
    int b = rest / H1;
    float out = 0.f;
    int vl2 = (lens[b] + 1) >> 1;
    if (h < vl2) {
        float a1 = b1[c], a2 = b2[c];
        #pragma unroll
        for (int r = 0; r < 3; ++r) {
            int t = 2 * h + r;
            if (t < Tn) {
                #pragma unroll
                for (int q = 0; q < 3; ++q) {
                    int f = 2 * w + q;
                    if (f < Fn) {
                        float v = in[(b * Tn + t) * Fn + f];
                        int wi = (r * 3 + q) * 64 + c;
                        a1 = fmaf(v, w1[wi], a1);
                        a2 = fmaf(v, w2[wi], a2);
                    }
                }
            }
        }
        out = fmaxf(a1, a2);
    }
    x1[idx] = f2bf(out);
}

// ---------------------------------------------------------------- K2: conv1 via MFMA implicit GEMM
__global__ void __launch_bounds__(256) k_conv1(
        const u16* __restrict__ x1, const u16* __restrict__ wt,
        const float* __restrict__ biasi, const int* __restrict__ lens,
        u16* __restrict__ x2) {
    constexpr int LD = 40;
    __shared__ u16 Al[2][128 * LD];
    __shared__ u16 Bl[2][128 * LD];
    __shared__ float bs_lds[128];

    int tid = threadIdx.x;
    int m0 = blockIdx.x * 128;
    int b = m0 / 10240;
    int vl4 = (lens[b] + 3) >> 2;

    if (tid < 128) bs_lds[tid] = biasi[tid];

    int srow = tid >> 1;
    int shalf = tid & 1;
    int am = m0 + srow;
    int aw = am % 20;
    int ah = (am / 20) % 512;
    const u16* abase = x1 + (((size_t)b * 1024 + 2 * ah) * 40 + 2 * aw) * 64;
    const u16* bbase = wt + srow * KC1;

    const uint4 uz = make_uint4(0, 0, 0, 0);
    uint4 na0, na1, nb0, nb1;
    {
        const u16* ap = abase + shalf * 16;
        na0 = *(const uint4*)(ap);
        na1 = *(const uint4*)(ap + 8);
        const u16* bp = bbase + shalf * 16;
        nb0 = *(const uint4*)(bp);
        nb1 = *(const uint4*)(bp + 8);
    }
    {
        u16* awp = &Al[0][srow * LD + shalf * 16];
        *(uint4*)awp = na0; *(uint4*)(awp + 8) = na1;
        u16* bwp = &Bl[0][srow * LD + shalf * 16];
        *(uint4*)bwp = nb0; *(uint4*)(bwp + 8) = nb1;
    }
    __syncthreads();

    int lane = tid & 63;
    int wid = tid >> 6;
    int mw = wid & 1, nw = wid >> 1;
    int frow = lane & 15;
    int koff = (lane >> 4) * 8;

    f32x4 acc[4][4] = {};
    int buf = 0;

    #pragma unroll
    for (int kc = 0; kc < 18; ++kc) {
        if (kc < 17) {
            int kn = kc + 1;
            int rq = kn >> 1, ci0 = (kn & 1) * 32;
            int r = rq / 3, q = rq - 3 * r;
            bool v = (2 * ah + r < 1024) && (2 * aw + q < 40);
            const u16* ap = abase + (r * 40 + q) * 64 + ci0 + shalf * 16;
            na0 = v ? *(const uint4*)(ap) : uz;
            na1 = v ? *(const uint4*)(ap + 8) : uz;
            const u16* bp = bbase + kn * 32 + shalf * 16;
            nb0 = *(const uint4*)(bp);
            nb1 = *(const uint4*)(bp + 8);
        }
        const u16* Ar = &Al[buf][(mw * 64 + frow) * LD + koff];
        const u16* Br = &Bl[buf][(nw * 64 + frow) * LD + koff];
        short8 af[4], bfr[4];
        #pragma unroll
        for (int s = 0; s < 4; ++s) {
            af[s]  = *(const short8*)(Ar + s * 16 * LD);
            bfr[s] = *(const short8*)(Br + s * 16 * LD);
        }
        #pragma unroll
        for (int sm = 0; sm < 4; ++sm)
            #pragma unroll
            for (int sn = 0; sn < 4; ++sn)
                acc[sm][sn] = __builtin_amdgcn_mfma_f32_16x16x32_bf16(
                    af[sm], bfr[sn], acc[sm][sn], 0, 0, 0);
        if (kc < 17) {
            buf ^= 1;
            u16* awp = &Al[buf][srow * LD + shalf * 16];
            *(uint4*)awp = na0; *(uint4*)(awp + 8) = na1;
            u16* bwp = &Bl[buf][srow * LD + shalf * 16];
            *(uint4*)bwp = nb0; *(uint4*)(bwp + 8) = nb1;
            __syncthreads();
        }
    }

    int orow = (lane >> 4) * 4;
    int ncol = lane & 15;
    #pragma unroll
    for (int sm = 0; sm < 4; ++sm) {
        #pragma unroll
        for (int sn = 0; sn < 4; ++sn) {
            int np = nw * 64 + sn * 16 + ncol;
            float bia = bs_lds[np];
            #pragma unroll
            for (int r = 0; r < 4; ++r) {
                float v = acc[sm][sn][r] + bia;
                float o = fmaxf(v, dpp_mov<0xB1>(v));
                if (!(lane & 1)) {
                    int gm = m0 + mw * 64 + sm * 16 + orow + r;
                    int w = gm % 20;
                    int h = (gm / 20) % 512;
                    float res = (h >= vl4) ? 0.f : o;
                    x2[((size_t)(b * 512 + h) * 20 + w) * 64 + (np >> 1)] = f2bf(res);
                }
            }
        }
    }
}

// ---------------------------------------------------------------- K3a: projection
__global__ void __launch_bounds__(256) k_proj(
        const u16* __restrict__ x2, const float* __restrict__ pw,
        const float* __restrict__ pb, float* __restrict__ proj) {
    int bs = blockIdx.x;
    int tid = threadIdx.x;
    int o = tid & 31, part = tid >> 5;
    const u16* row = &x2[(size_t)bs * PK];
    float acc = 0.f;
    int k0 = part * 160;
    #pragma unroll 8
    for (int k = 0; k < 160; ++k)
        acc = fmaf(bf2f(row[k0 + k]), pw[(k0 + k) * 32 + o], acc);
    __shared__ float red[256];
    red[tid] = acc;
    __syncthreads();
    if (tid < 32) {
        float s = 0.f;
        #pragma unroll
        for (int p = 0; p < 8; ++p) s += red[p * 32 + tid];
        proj[bs * 32 + tid] = s + pb[tid];
    }
}

// ---------------------------------------------------------------- K3b: enc conv + mask + squash + LN
__global__ void __launch_bounds__(256) k_enc(
        const float* __restrict__ proj,
        const float* __restrict__ ew1, const float* __restrict__ eb1,
        const float* __restrict__ ew2, const float* __restrict__ eb2,
        const int* __restrict__ lens, float* __restrict__ emb0) {
    int bs = blockIdx.x;
    int s = bs & (Sn - 1);
    int b = bs >> 9;
    int tid = threadIdx.x;
    __shared__ float rows[3][32];
    __shared__ float red[8];
    if (tid < 96) {
        int r = tid >> 5, n = tid & 31;
        int sr = s - 1 + r;
        rows[r][n] = (sr >= 0 && sr < Sn) ? proj[(b * Sn + sr) * 32 + n] : 0.f;
    }
    __syncthreads();

    int n = tid >> 3, d = tid & 7;
    float a1 = eb1[d], a2 = eb2[d];
    #pragma unroll
    for (int r = 0; r < 3; ++r) {
        #pragma unroll
        for (int q = 0; q < 3; ++q) {
            int nn = n - 1 + q;
            if (nn >= 0 && nn < 32) {
                float v = rows[r][nn];
                int wi = (r * 3 + q) * 8 + d;
                a1 = fmaf(v, ew1[wi], a1);
                a2 = fmaf(v, ew2[wi], a2);
            }
        }
    }
    float x = fmaxf(a1, a2);
    int vl4 = (lens[b] + 3) >> 2;
    if (s >= vl4) x = 0.f;

    float sq = sum8(x * x);
    x = x * (sq / (1.f + sq) * rsqrtf(sq + 1e-6f));

    float2 ss = block_sum2(x, x * x, tid, red);
    float mu = ss.x * (1.f / 256.f);
    float var = ss.y * (1.f / 256.f) - mu * mu;
    emb0[bs * 256 + tid] = (x - mu) * rsqrtf(var + 1e-3f);
}

// ---------------------------------------------------------------- K4: caps layer 0
__global__ void __launch_bounds__(256, 2) k_caps0(
        const float* __restrict__ embin, const u16* __restrict__ W0,
        const float* __restrict__ B0, float* __restrict__ embout) {
    int bs = blockIdx.x;
    int s = bs & (Sn - 1);
    int b = bs >> 9;
    int tid = threadIdx.x;
    int o = tid >> 3;

    __shared__ __align__(16) u32 win2[I0 * 4];   // f16-pair packed [i][k/2]
    __shared__ float blog[I0 * 33];
    __shared__ float cct[O0 * CP];
    __shared__ float red[8];

    for (int idx = tid; idx < I0 * 4; idx += 256) {
        int i = idx >> 2, kk = idx & 3;
        int sr = s + (i >> 5) - 1;
        float a = 0.f, bv = 0.f;
        if (sr >= 0 && sr < Sn) {
            const float* p = &embin[(b * Sn + sr) * 256 + (i & 31) * 8 + kk * 2];
            a = p[0]; bv = p[1];
        }
        win2[idx] = pack2h(a, bv);
    }
    for (int i = tid; i < I0 * 33; i += 256) blog[i] = 0.f;
    __syncthreads();

    // u_hat via v_dot2_f32_f16: u[i] = B0[i,o,d] + sum_k W0[i,od,k]*win[i,k]
    float u_reg[I0];
    {
        const uint4* Wv = (const uint4*)W0;        // 8 f16 per (i,od)
        const uint4* wl = (const uint4*)win2;      // 8 f16 per i (broadcast)
        #pragma unroll
        for (int i = 0; i < I0; ++i) {
            uint4 wv = Wv[i * 256 + tid];
            uint4 ww = wl[i];
            float acc = B0[i * 256 + tid];
            acc = dot2(wv.x, ww.x, acc);
            acc = dot2(wv.y, ww.y, acc);
            acc = dot2(wv.z, ww.z, acc);
            acc = dot2(wv.w, ww.w, acc);
            u_reg[i] = acc;
        }
    }

    float vval = 0.f;
    for (int it = 0; it < 3; ++it) {
        // softmax over o per i — 2 threads per i, no max-sub (logits bounded)
        if (tid < 192) {
            int i = tid >> 1, hf = tid & 1;
            int o0 = hf * 16;
            float ex[16];
            float ssum = 0.f;
            #pragma unroll
            for (int j = 0; j < 16; ++j) {
                ex[j] = __expf(blog[i * 33 + o0 + j]);
                ssum += ex[j];
            }
            ssum += dpp_mov<0xB1>(ssum);            // partner (xor1) sum
            float inv = __builtin_amdgcn_rcpf(ssum);
            #pragma unroll
            for (int j = 0; j < 16; ++j)
                cct[(o0 + j) * CP + i] = ex[j] * inv;
        }
        __syncthreads();
        float sv = 0.f;
        {
            const float* cr = &cct[o * CP];
            #pragma unroll
            for (int i = 0; i < I0; ++i) sv = fmaf(cr[i], u_reg[i], sv);
        }
        float sq = sum8(sv * sv);
        vval = sv * (sq / (1.f + sq) * rsqrtf(sq + 1e-6f));
        if (it < 2) {
            #pragma unroll
            for (int i = 0; i < I0; ++i) {
                float p = sum8(u_reg[i] * vval);
                if ((tid & 7) == 0) blog[i * 33 + o] += p;
            }
            __syncthreads();
        }
    }

    float2 ss = block_sum2(vval, vval * vval, tid, red);
    float mu = ss.x * (1.f / 256.f);
    float var = ss.y * (1.f / 256.f) - mu * mu;
    embout[bs * 256 + tid] = (vval - mu) * rsqrtf(var + 1e-3f);
}

// ---------------------------------------------------------------- K5: caps layer 1 + epilogue
__global__ void __launch_bounds__(256, 2) k_caps1(
        const float* __restrict__ embin, const u16* __restrict__ W1,
        const float* __restrict__ B1, float* __restrict__ outp) {
    int bs = blockIdx.x;
    int s = bs & (Sn - 1);
    int b = bs >> 9;
    int tid = threadIdx.x;
    int o = tid >> 3, d = tid & 7;
    bool valid = (o < O1);
    int oc = valid ? o : (O1 - 1);
    int ocd = oc * 8 + d;

    __shared__ __align__(16) u32 win2[I0 * 4];
    __shared__ float blog[I0 * 33];
    __shared__ float cct[O1 * CP];
    __shared__ float red[8];
    __shared__ float lenb[O1];
    __shared__ float mv2[2];

    for (int idx = tid; idx < I0 * 4; idx += 256) {
        int i = idx >> 2, kk = idx & 3;
        int sr = s + (i >> 5) - 1;
        float a = 0.f, bv = 0.f;
        if (sr >= 0 && sr < Sn) {
            const float* p = &embin[(b * Sn + sr) * 256 + (i & 31) * 8 + kk * 2];
            a = p[0]; bv = p[1];
        }
        win2[idx] = pack2h(a, bv);
    }
    for (int i = tid; i < I0 * 33; i += 256) blog[i] = 0.f;
    __syncthreads();

    float u_reg[I0];
    {
        const uint4* Wv = (const uint4*)W1;
        const uint4* wl = (const uint4*)win2;
        #pragma unroll
        for (int i = 0; i < I0; ++i) {
            uint4 wv = Wv[i * 248 + ocd];
            uint4 ww = wl[i];
            float acc = B1[i * 248 + ocd];
            acc = dot2(wv.x, ww.x, acc);
            acc = dot2(wv.y, ww.y, acc);
            acc = dot2(wv.z, ww.z, acc);
            acc = dot2(wv.w, ww.w, acc);
            u_reg[i] = acc;
        }
    }

    float vval = 0.f;
    for (int it = 0; it < 3; ++it) {
        // softmax over o=1..30 (class 0 masked -> coupling 0); 2 threads per i
        if (tid < 192) {
            int i = tid >> 1, hf = tid & 1;
            int lo = hf ? 16 : 1;
            float ex[16];
            float ssum = 0.f;
            #pragma unroll
            for (int j = 0; j < 15; ++j) {
                ex[j] = __expf(blog[i * 33 + lo + j]);
                ssum += ex[j];
            }
            ssum += dpp_mov<0xB1>(ssum);
            float inv = __builtin_amdgcn_rcpf(ssum);
            if (!hf) cct[i] = 0.f;                   // class 0
            #pragma unroll
            for (int j = 0; j < 15; ++j)
                cct[(lo + j) * CP + i] = ex[j] * inv;
        }
        __syncthreads();
        float sv = 0.f;
        {
            const float* cr = &cct[oc * CP];
            #pragma unroll
            for (int i = 0; i < I0; ++i) sv = fmaf(cr[i], u_reg[i], sv);
        }
        float sq = sum8(sv * sv);
        vval = sv * (sq / (1.f + sq) * rsqrtf(sq + 1e-6f));
        if (!valid) vval = 0.f;
        if (it < 2) {
            #pragma unroll
            for (int i = 0; i < I0; ++i) {
                float p = sum8(u_reg[i] * vval);
                if ((tid & 7) == 0 && valid) blog[i * 33 + o] += p;
            }
            __syncthreads();
        }
    }

    float2 ss = block_sum2(vval, vval * vval, tid, red);
    float mu = ss.x * (1.f / 248.f);
    float var = ss.y * (1.f / 248.f) - mu * mu;
    float y = (vval - mu) * rsqrtf(var + 1e-3f);

    float sq = sum8(y * y);
    if (valid && (tid & 7) == 0) lenb[o] = sqrtf(sq + 1e-6f);
    __syncthreads();

    if (tid == 0) {
        float s1 = 0.f, s2 = 0.f;
        for (int oo = 0; oo < O1; ++oo) { float t = lenb[oo]; s1 += t; s2 += t * t; }
        float m2 = s1 / 31.f;
        mv2[0] = m2;
        mv2[1] = rsqrtf(s2 / 31.f - m2 * m2 + 1e-3f);
    }
    __syncthreads();
    if (tid < O1)
        outp[(size_t)bs * O1 + tid] = (lenb[tid] - mv2[0]) * mv2[1];
}

// ---------------------------------------------------------------- launch
extern "C" void kernel_launch(void* const* d_in, const int* in_sizes, int n_in,
                              void* d_out, int out_size, void* d_ws, size_t ws_size,
                              hipStream_t stream) {
    const float* inputs = (const float*)d_in[0];
    const float* c0w1 = (const float*)d_in[1];
    const float* c0b1 = (const float*)d_in[2];
    const float* c0w2 = (const float*)d_in[3];
    const float* c0b2 = (const float*)d_in[4];
    const float* c1w1 = (const float*)d_in[5];
    const float* c1b1 = (const float*)d_in[6];
    const float* c1w2 = (const float*)d_in[7];
    const float* c1b2 = (const float*)d_in[8];
    const float* pw   = (const float*)d_in[9];
    const float* pb   = (const float*)d_in[10];
    const float* ew1  = (const float*)d_in[11];
    const float* eb1  = (const float*)d_in[12];
    const float* ew2  = (const float*)d_in[13];
    const float* eb2  = (const float*)d_in[14];
    const float* W0   = (const float*)d_in[15];
    const float* B0   = (const float*)d_in[16];
    const float* W1   = (const float*)d_in[17];
    const float* B1   = (const float*)d_in[18];
    const int* lens = (const int*)d_in[19];

    char* ws = (char*)d_ws;
    u16*   x1    = (u16*)(ws);                       // 41,943,040 B
    u16*   x2    = (u16*)(ws + 41943040);            // 10,485,760 B (bf16)
    float* proj  = (float*)(ws + 52428800);          //    524,288 B
    float* emb0  = (float*)(ws + 52953088);          //  4,194,304 B
    float* emb1  = (float*)(ws + 57147392);          //  4,194,304 B
    u16*   W0h   = (u16*)(ws + 61341696);            //    393,216 B (f16)
    u16*   W1h   = (u16*)(ws + 61734912);            //    380,928 B (f16)
    u16*   wt    = (u16*)(ws + 62115840);            //    147,456 B
    float* biasi = (float*)(ws + 62263296);          //        512 B (end ~62.3 MB)

    k_prep<<<(NW0 + 255) / 256, 256, 0, stream>>>(
        W0, W1, c1w1, c1b1, c1w2, c1b2, W0h, W1h, wt, biasi);
    k_conv0<<<(Bn * H1 * W1n * NF) / 256, 256, 0, stream>>>(
        inputs, c0w1, c0b1, c0w2, c0b2, lens, x1);
    k_conv1<<<640, 256, 0, stream>>>(x1, wt, biasi, lens, x2);
    k_proj<<<Bn * Sn, 256, 0, stream>>>(x2, pw, pb, proj);
    k_enc<<<Bn * Sn, 256, 0, stream>>>(proj, ew1, eb1, ew2, eb2, lens, emb0);
    k_caps0<<<Bn * Sn, 256, 0, stream>>>(emb0, W0h, B0, emb1);
    k_caps1<<<Bn * Sn, 256, 0, stream>>>(emb1, W1h, B1, (float*)d_out);
}

// Round 9
// 451.350 us; speedup vs baseline: 1.7111x; 1.1205x over previous
//
#include <hip/hip_runtime.h>

typedef unsigned short u16;
typedef unsigned int u32;
typedef short short8 __attribute__((ext_vector_type(8)));
typedef float f32x4 __attribute__((ext_vector_type(4)));
typedef _Float16 h2 __attribute__((ext_vector_type(2)));
typedef __fp16 fp16v2 __attribute__((ext_vector_type(2)));

#define DEV static __device__ __forceinline__

DEV float bf2f(u16 v) { return __uint_as_float((u32)v << 16); }
DEV u16 f2bf(float f) {
    u32 x = __float_as_uint(f);
    return (u16)((x + 0x7fffu + ((x >> 16) & 1u)) >> 16);  // RNE
}
DEV u16 f2h(float f) {
    union { _Float16 h; u16 u; } c; c.h = (_Float16)f; return c.u;
}
DEV u32 pack2h(float a, float b) {
#if __has_builtin(__builtin_amdgcn_cvt_pkrtz)
    union { fp16v2 h; u32 u; } c;
    c.h = __builtin_amdgcn_cvt_pkrtz(a, b);
    return c.u;
#else
    union { u32 u; _Float16 h[2]; } c;
    c.h[0] = (_Float16)a; c.h[1] = (_Float16)b; return c.u;
#endif
}
DEV h2 u2h(u32 x) { union { u32 u; h2 h; } c; c.u = x; return c.h; }
DEV u32 h2u(h2 v) { union { h2 h; u32 u; } c; c.h = v; return c.u; }

#if __has_builtin(__builtin_amdgcn_fdot2)
DEV float dot2(u32 a, u32 b, float c) {
    return __builtin_amdgcn_fdot2(u2h(a), u2h(b), c, false);
}
#else
DEV float dot2(u32 a, u32 b, float c) {
    h2 ha = u2h(a), hb = u2h(b);
    c = fmaf((float)ha[0], (float)hb[0], c);
    return fmaf((float)ha[1], (float)hb[1], c);
}
#endif

constexpr int Bn = 8, Tn = 2048, Fn = 80, NF = 64;
constexpr int H1 = 1024, W1n = 40;          // after conv0 (stride 2)
constexpr int Sn = 512,  W2n = 20;          // after conv1 (stride 2)
constexpr int PK = 1280;                    // 20*64
constexpr int I0 = 96;                      // 32 capsules * window 3
constexpr int O0 = 32;                      // conv capsules
constexpr int O1 = 31;                      // class capsules
constexpr int CPW = 52;                     // packed-c row stride (u32; 16B aligned)
constexpr int NW0 = I0 * O0 * 8 * 8;        // 196608
constexpr int NW1 = I0 * O1 * 8 * 8;        // 190464
constexpr int KC1 = 576;                    // conv1 GEMM K (9*64)

// ---------------------------------------------------------------- DPP helpers
template <int CTRL>
DEV float dpp_mov(float x) {
    return __int_as_float(__builtin_amdgcn_update_dpp(
        0, __float_as_int(x), CTRL, 0xF, 0xF, true));
}
template <int CTRL>
DEV u32 dppu(u32 x) {
    return (u32)__builtin_amdgcn_update_dpp(0, (int)x, CTRL, 0xF, 0xF, true);
}
DEV float sum8(float x) {
    x += dpp_mov<0xB1>(x);    // quad_perm xor1
    x += dpp_mov<0x4E>(x);    // quad_perm xor2
    x += dpp_mov<0x141>(x);   // row_half_mirror
    return x;
}
DEV u32 sum8h(u32 x) {        // packed f16 pair, 8-lane sum of both halves
    x = h2u(u2h(x) + u2h(dppu<0xB1>(x)));
    x = h2u(u2h(x) + u2h(dppu<0x4E>(x)));
    x = h2u(u2h(x) + u2h(dppu<0x141>(x)));
    return x;
}

// ---------------------------------------------------------------- block reduce (4 waves)
DEV float2 block_sum2(float a, float b, int tid, float* lds /*>=8 floats*/) {
    #pragma unroll
    for (int m = 1; m < 64; m <<= 1) {
        a += __shfl_xor(a, m);
        b += __shfl_xor(b, m);
    }
    int wid = tid >> 6;
    __syncthreads();
    if ((tid & 63) == 0) { lds[wid * 2] = a; lds[wid * 2 + 1] = b; }
    __syncthreads();
    float ra = lds[0] + lds[2] + lds[4] + lds[6];
    float rb = lds[1] + lds[3] + lds[5] + lds[7];
    return make_float2(ra, rb);
}

// ---------------------------------------------------------------- K0: prep
__global__ void __launch_bounds__(256) k_prep(
        const float* __restrict__ w0, const float* __restrict__ w1c,
        const float* __restrict__ cw1, const float* __restrict__ cb1,
        const float* __restrict__ cw2, const float* __restrict__ cb2,
        u16* __restrict__ w0h, u16* __restrict__ w1h,
        u16* __restrict__ wt, float* __restrict__ biasi) {
    int idx = blockIdx.x * 256 + threadIdx.x;
    if (idx < NW0) w0h[idx] = f2h(w0[idx]);
    if (idx < NW1) w1h[idx] = f2h(w1c[idx]);
    if (idx < 128 * KC1) {
        int n = idx / KC1, k = idx - n * KC1;
        int c = n >> 1, s = n & 1;
        const float* w = s ? cw2 : cw1;   // [3,3,64,64] flat: k*64 + c
        wt[idx] = f2bf(w[k * 64 + c]);
    }
    if (idx < 128) {
        int c = idx >> 1, s = idx & 1;
        biasi[idx] = (s ? cb2 : cb1)[c];
    }
}

// ---------------------------------------------------------------- K1: conv0 maxout
__global__ void __launch_bounds__(256) k_conv0(
        const float* __restrict__ in,
        const float* __restrict__ w1, const float* __restrict__ b1,
        const float* __restrict__ w2, const float* __restrict__ b2,
        const int* __restrict__ lens, u16* __restrict__ x1) {
    int idx = blockIdx.x * 256 + threadIdx.x;
    if (idx >= Bn * H1 * W1n * NF) return;
    int c = idx & 63;
    int rest = idx >> 6;
    int w = rest % W1n; rest /= W1n;
    int h = rest % H1;
    int b = rest / H1;
    float out = 0.f;
    int vl2 = (lens[b] + 1) >> 1;
    if (h < vl2) {
        float a1 = b1[c], a2 = b2[c];
        #pragma unroll
        for (int r = 0; r < 3; ++r) {
            int t = 2 * h + r;
            if (t < Tn) {
                #pragma unroll
                for (int q = 0; q < 3; ++q) {
                    int f = 2 * w + q;
                    if (f < Fn) {
                        float v = in[(b * Tn + t) * Fn + f];
                        int wi = (r * 3 + q) * 64 + c;
                        a1 = fmaf(v, w1[wi], a1);
                        a2 = fmaf(v, w2[wi], a2);
                    }
                }
            }
        }
        out = fmaxf(a1, a2);
    }
    x1[idx] = f2bf(out);
}

// ---------------------------------------------------------------- K2: conv1 via MFMA implicit GEMM
__global__ void __launch_bounds__(256) k_conv1(
        const u16* __restrict__ x1, const u16* __restrict__ wt,
        const float* __restrict__ biasi, const int* __restrict__ lens,
        u16* __restrict__ x2) {
    constexpr int LD = 40;
    __shared__ u16 Al[2][128 * LD];
    __shared__ u16 Bl[2][128 * LD];
    __shared__ float bs_lds[128];

    int tid = threadIdx.x;
    int m0 = blockIdx.x * 128;
    int b = m0 / 10240;
    int vl4 = (lens[b] + 3) >> 2;

    if (tid < 128) bs_lds[tid] = biasi[tid];

    int srow = tid >> 1;
    int shalf = tid & 1;
    int am = m0 + srow;
    int aw = am % 20;
    int ah = (am / 20) % 512;
    const u16* abase = x1 + (((size_t)b * 1024 + 2 * ah) * 40 + 2 * aw) * 64;
    const u16* bbase = wt + srow * KC1;

    const uint4 uz = make_uint4(0, 0, 0, 0);
    uint4 na0, na1, nb0, nb1;
    {
        const u16* ap = abase + shalf * 16;
        na0 = *(const uint4*)(ap);
        na1 = *(const uint4*)(ap + 8);
        const u16* bp = bbase + shalf * 16;
        nb0 = *(const uint4*)(bp);
        nb1 = *(const uint4*)(bp + 8);
    }
    {
        u16* awp = &Al[0][srow * LD + shalf * 16];
        *(uint4*)awp = na0; *(uint4*)(awp + 8) = na1;
        u16* bwp = &Bl[0][srow * LD + shalf * 16];
        *(uint4*)bwp = nb0; *(uint4*)(bwp + 8) = nb1;
    }
    __syncthreads();

    int lane = tid & 63;
    int wid = tid >> 6;
    int mw = wid & 1, nw = wid >> 1;
    int frow = lane & 15;
    int koff = (lane >> 4) * 8;

    f32x4 acc[4][4] = {};
    int buf = 0;

    #pragma unroll
    for (int kc = 0; kc < 18; ++kc) {
        if (kc < 17) {
            int kn = kc + 1;
            int rq = kn >> 1, ci0 = (kn & 1) * 32;
            int r = rq / 3, q = rq - 3 * r;
            bool v = (2 * ah + r < 1024) && (2 * aw + q < 40);
            const u16* ap = abase + (r * 40 + q) * 64 + ci0 + shalf * 16;
            na0 = v ? *(const uint4*)(ap) : uz;
            na1 = v ? *(const uint4*)(ap + 8) : uz;
            const u16* bp = bbase + kn * 32 + shalf * 16;
            nb0 = *(const uint4*)(bp);
            nb1 = *(const uint4*)(bp + 8);
        }
        const u16* Ar = &Al[buf][(mw * 64 + frow) * LD + koff];
        const u16* Br = &Bl[buf][(nw * 64 + frow) * LD + koff];
        short8 af[4], bfr[4];
        #pragma unroll
        for (int s = 0; s < 4; ++s) {
            af[s]  = *(const short8*)(Ar + s * 16 * LD);
            bfr[s] = *(const short8*)(Br + s * 16 * LD);
        }
        #pragma unroll
        for (int sm = 0; sm < 4; ++sm)
            #pragma unroll
            for (int sn = 0; sn < 4; ++sn)
                acc[sm][sn] = __builtin_amdgcn_mfma_f32_16x16x32_bf16(
                    af[sm], bfr[sn], acc[sm][sn], 0, 0, 0);
        if (kc < 17) {
            buf ^= 1;
            u16* awp = &Al[buf][srow * LD + shalf * 16];
            *(uint4*)awp = na0; *(uint4*)(awp + 8) = na1;
            u16* bwp = &Bl[buf][srow * LD + shalf * 16];
            *(uint4*)bwp = nb0; *(uint4*)(bwp + 8) = nb1;
            __syncthreads();
        }
    }

    int orow = (lane >> 4) * 4;
    int ncol = lane & 15;
    #pragma unroll
    for (int sm = 0; sm < 4; ++sm) {
        #pragma unroll
        for (int sn = 0; sn < 4; ++sn) {
            int np = nw * 64 + sn * 16 + ncol;
            float bia = bs_lds[np];
            #pragma unroll
            for (int r = 0; r < 4; ++r) {
                float v = acc[sm][sn][r] + bia;
                float o = fmaxf(v, dpp_mov<0xB1>(v));
                if (!(lane & 1)) {
                    int gm = m0 + mw * 64 + sm * 16 + orow + r;
                    int w = gm % 20;
                    int h = (gm / 20) % 512;
                    float res = (h >= vl4) ? 0.f : o;
                    x2[((size_t)(b * 512 + h) * 20 + w) * 64 + (np >> 1)] = f2bf(res);
                }
            }
        }
    }
}

// ---------------------------------------------------------------- K3a: projection
__global__ void __launch_bounds__(256) k_proj(
        const u16* __restrict__ x2, const float* __restrict__ pw,
        const float* __restrict__ pb, float* __restrict__ proj) {
    int bs = blockIdx.x;
    int tid = threadIdx.x;
    int o = tid & 31, part = tid >> 5;
    const u16* row = &x2[(size_t)bs * PK];
    float acc = 0.f;
    int k0 = part * 160;
    #pragma unroll 8
    for (int k = 0; k < 160; ++k)
        acc = fmaf(bf2f(row[k0 + k]), pw[(k0 + k) * 32 + o], acc);
    __shared__ float red[256];
    red[tid] = acc;
    __syncthreads();
    if (tid < 32) {
        float s = 0.f;
        #pragma unroll
        for (int p = 0; p < 8; ++p) s += red[p * 32 + tid];
        proj[bs * 32 + tid] = s + pb[tid];
    }
}

// ---------------------------------------------------------------- K3b: enc conv + mask + squash + LN
__global__ void __launch_bounds__(256) k_enc(
        const float* __restrict__ proj,
        const float* __restrict__ ew1, const float* __restrict__ eb1,
        const float* __restrict__ ew2, const float* __restrict__ eb2,
        const int* __restrict__ lens, float* __restrict__ emb0) {
    int bs = blockIdx.x;
    int s = bs & (Sn - 1);
    int b = bs >> 9;
    int tid = threadIdx.x;
    __shared__ float rows[3][32];
    __shared__ float red[8];
    if (tid < 96) {
        int r = tid >> 5, n = tid & 31;
        int sr = s - 1 + r;
        rows[r][n] = (sr >= 0 && sr < Sn) ? proj[(b * Sn + sr) * 32 + n] : 0.f;
    }
    __syncthreads();

    int n = tid >> 3, d = tid & 7;
    float a1 = eb1[d], a2 = eb2[d];
    #pragma unroll
    for (int r = 0; r < 3; ++r) {
        #pragma unroll
        for (int q = 0; q < 3; ++q) {
            int nn = n - 1 + q;
            if (nn >= 0 && nn < 32) {
                float v = rows[r][nn];
                int wi = (r * 3 + q) * 8 + d;
                a1 = fmaf(v, ew1[wi], a1);
                a2 = fmaf(v, ew2[wi], a2);
            }
        }
    }
    float x = fmaxf(a1, a2);
    int vl4 = (lens[b] + 3) >> 2;
    if (s >= vl4) x = 0.f;

    float sq = sum8(x * x);
    x = x * (sq / (1.f + sq) * rsqrtf(sq + 1e-6f));

    float2 ss = block_sum2(x, x * x, tid, red);
    float mu = ss.x * (1.f / 256.f);
    float var = ss.y * (1.f / 256.f) - mu * mu;
    emb0[bs * 256 + tid] = (x - mu) * rsqrtf(var + 1e-3f);
}

// ---------------------------------------------------------------- K4: caps layer 0 (packed-f16 u)
__global__ void __launch_bounds__(256, 4) k_caps0(
        const float* __restrict__ embin, const u16* __restrict__ W0,
        const float* __restrict__ B0, float* __restrict__ embout) {
    int bs = blockIdx.x;
    int s = bs & (Sn - 1);
    int b = bs >> 9;
    int tid = threadIdx.x;
    int o = tid >> 3;

    __shared__ __align__(16) u32 win2[I0 * 4];   // f16-pair packed [i][k/2]
    __shared__ float blog[I0 * 33];
    __shared__ __align__(16) u32 cpk[O0 * CPW];  // couplings f16 pairs [o][i/2]
    __shared__ float red[8];
    u16* cph = (u16*)cpk;

    for (int idx = tid; idx < I0 * 4; idx += 256) {
        int i = idx >> 2, kk = idx & 3;
        int sr = s + (i >> 5) - 1;
        float a = 0.f, bv = 0.f;
        if (sr >= 0 && sr < Sn) {
            const float* p = &embin[(b * Sn + sr) * 256 + (i & 31) * 8 + kk * 2];
            a = p[0]; bv = p[1];
        }
        win2[idx] = pack2h(a, bv);
    }
    for (int i = tid; i < I0 * 33; i += 256) blog[i] = 0.f;
    __syncthreads();

    // u_hat packed: u_pk[ii] = f16(u[2ii]), f16(u[2ii+1])
    u32 u_pk[48];
    {
        const uint4* Wv = (const uint4*)W0;
        const uint4* wl = (const uint4*)win2;
        #pragma unroll
        for (int ii = 0; ii < 48; ++ii) {
            int i0 = 2 * ii, i1 = 2 * ii + 1;
            uint4 wv0 = Wv[i0 * 256 + tid];
            uint4 wv1 = Wv[i1 * 256 + tid];
            uint4 ww0 = wl[i0];
            uint4 ww1 = wl[i1];
            float a0 = B0[i0 * 256 + tid];
            float a1 = B0[i1 * 256 + tid];
            a0 = dot2(wv0.x, ww0.x, a0);
            a0 = dot2(wv0.y, ww0.y, a0);
            a0 = dot2(wv0.z, ww0.z, a0);
            a0 = dot2(wv0.w, ww0.w, a0);
            a1 = dot2(wv1.x, ww1.x, a1);
            a1 = dot2(wv1.y, ww1.y, a1);
            a1 = dot2(wv1.z, ww1.z, a1);
            a1 = dot2(wv1.w, ww1.w, a1);
            u_pk[ii] = pack2h(a0, a1);
        }
    }

    float vval = 0.f;
    for (int it = 0; it < 3; ++it) {
        // softmax over o per i — 2 threads per i, write packed f16 c
        if (tid < 192) {
            int i = tid >> 1, hf = tid & 1;
            int o0 = hf * 16;
            float ex[16];
            float ssum = 0.f;
            #pragma unroll
            for (int j = 0; j < 16; ++j) {
                ex[j] = __expf(blog[i * 33 + o0 + j]);
                ssum += ex[j];
            }
            ssum += dpp_mov<0xB1>(ssum);            // partner (xor1) sum
            float inv = __builtin_amdgcn_rcpf(ssum);
            #pragma unroll
            for (int j = 0; j < 16; ++j)
                cph[(o0 + j) * (CPW * 2) + i] = f2h(ex[j] * inv);
        }
        __syncthreads();
        // sv = sum_i c[i,o]*u[i,o,d] via packed dot2
        float sv = 0.f;
        {
            const uint4* cr = (const uint4*)&cpk[o * CPW];
            #pragma unroll
            for (int q4 = 0; q4 < 12; ++q4) {
                uint4 cc = cr[q4];
                sv = dot2(u_pk[q4 * 4 + 0], cc.x, sv);
                sv = dot2(u_pk[q4 * 4 + 1], cc.y, sv);
                sv = dot2(u_pk[q4 * 4 + 2], cc.z, sv);
                sv = dot2(u_pk[q4 * 4 + 3], cc.w, sv);
            }
        }
        float sq = sum8(sv * sv);
        vval = sv * (sq / (1.f + sq) * rsqrtf(sq + 1e-6f));
        if (it < 2) {
            // b[i,o] += sum_d u[i,o,d]*v[o,d] — packed pair per step
            u32 vv = pack2h(vval, vval);
            #pragma unroll
            for (int ii = 0; ii < 48; ++ii) {
                u32 pr = h2u(u2h(u_pk[ii]) * u2h(vv));
                u32 p = sum8h(pr);
                if ((tid & 7) == 0) {
                    h2 ph = u2h(p);
                    blog[(2 * ii) * 33 + o]     += (float)ph[0];
                    blog[(2 * ii + 1) * 33 + o] += (float)ph[1];
                }
            }
            __syncthreads();
        }
    }

    float2 ss = block_sum2(vval, vval * vval, tid, red);
    float mu = ss.x * (1.f / 256.f);
    float var = ss.y * (1.f / 256.f) - mu * mu;
    embout[bs * 256 + tid] = (vval - mu) * rsqrtf(var + 1e-3f);
}

// ---------------------------------------------------------------- K5: caps layer 1 + epilogue (packed-f16 u)
__global__ void __launch_bounds__(256, 4) k_caps1(
        const float* __restrict__ embin, const u16* __restrict__ W1,
        const float* __restrict__ B1, float* __restrict__ outp) {
    int bs = blockIdx.x;
    int s = bs & (Sn - 1);
    int b = bs >> 9;
    int tid = threadIdx.x;
    int o = tid >> 3, d = tid & 7;
    bool valid = (o < O1);
    int oc = valid ? o : (O1 - 1);
    int ocd = oc * 8 + d;

    __shared__ __align__(16) u32 win2[I0 * 4];
    __shared__ float blog[I0 * 33];
    __shared__ __align__(16) u32 cpk[O1 * CPW];
    __shared__ float red[8];
    __shared__ float lenb[O1];
    __shared__ float mv2[2];
    u16* cph = (u16*)cpk;

    for (int idx = tid; idx < I0 * 4; idx += 256) {
        int i = idx >> 2, kk = idx & 3;
        int sr = s + (i >> 5) - 1;
        float a = 0.f, bv = 0.f;
        if (sr >= 0 && sr < Sn) {
            const float* p = &embin[(b * Sn + sr) * 256 + (i & 31) * 8 + kk * 2];
            a = p[0]; bv = p[1];
        }
        win2[idx] = pack2h(a, bv);
    }
    for (int i = tid; i < I0 * 33; i += 256) blog[i] = 0.f;
    for (int i = tid; i < CPW; i += 256) cpk[i] = 0;   // class-0 row: coupling 0 forever
    __syncthreads();

    u32 u_pk[48];
    {
        const uint4* Wv = (const uint4*)W1;
        const uint4* wl = (const uint4*)win2;
        #pragma unroll
        for (int ii = 0; ii < 48; ++ii) {
            int i0 = 2 * ii, i1 = 2 * ii + 1;
            uint4 wv0 = Wv[i0 * 248 + ocd];
            uint4 wv1 = Wv[i1 * 248 + ocd];
            uint4 ww0 = wl[i0];
            uint4 ww1 = wl[i1];
            float a0 = B1[i0 * 248 + ocd];
            float a1 = B1[i1 * 248 + ocd];
            a0 = dot2(wv0.x, ww0.x, a0);
            a0 = dot2(wv0.y, ww0.y, a0);
            a0 = dot2(wv0.z, ww0.z, a0);
            a0 = dot2(wv0.w, ww0.w, a0);
            a1 = dot2(wv1.x, ww1.x, a1);
            a1 = dot2(wv1.y, ww1.y, a1);
            a1 = dot2(wv1.z, ww1.z, a1);
            a1 = dot2(wv1.w, ww1.w, a1);
            u_pk[ii] = pack2h(a0, a1);
        }
    }

    float vval = 0.f;
    for (int it = 0; it < 3; ++it) {
        // softmax over o=1..30 (class 0 masked); 2 threads per i
        if (tid < 192) {
            int i = tid >> 1, hf = tid & 1;
            int lo = hf ? 16 : 1;
            float ex[15];
            float ssum = 0.f;
            #pragma unroll
            for (int j = 0; j < 15; ++j) {
                ex[j] = __expf(blog[i * 33 + lo + j]);
                ssum += ex[j];
            }
            ssum += dpp_mov<0xB1>(ssum);
            float inv = __builtin_amdgcn_rcpf(ssum);
            #pragma unroll
            for (int j = 0; j < 15; ++j)
                cph[(lo + j) * (CPW * 2) + i] = f2h(ex[j] * inv);
        }
        __syncthreads();
        float sv = 0.f;
        {
            const uint4* cr = (const uint4*)&cpk[oc * CPW];
            #pragma unroll
            for (int q4 = 0; q4 < 12; ++q4) {
                uint4 cc = cr[q4];
                sv = dot2(u_pk[q4 * 4 + 0], cc.x, sv);
                sv = dot2(u_pk[q4 * 4 + 1], cc.y, sv);
                sv = dot2(u_pk[q4 * 4 + 2], cc.z, sv);
                sv = dot2(u_pk[q4 * 4 + 3], cc.w, sv);
            }
        }
        float sq = sum8(sv * sv);
        vval = sv * (sq / (1.f + sq) * rsqrtf(sq + 1e-6f));
        if (!valid) vval = 0.f;
        if (it < 2) {
            u32 vv = pack2h(vval, vval);
            #pragma unroll
            for (int ii = 0; ii < 48; ++ii) {
                u32 pr = h2u(u2h(u_pk[ii]) * u2h(vv));
                u32 p = sum8h(pr);
                if ((tid & 7) == 0 && valid) {
                    h2 ph = u2h(p);
                    blog[(2 * ii) * 33 + o]     += (float)ph[0];
                    blog[(2 * ii + 1) * 33 + o] += (float)ph[1];
                }
            }
            __syncthreads();
        }
    }

    float2 ss = block_sum2(vval, vval * vval, tid, red);
    float mu = ss.x * (1.f / 248.f);
    float var = ss.y * (1.f / 248.f) - mu * mu;
    float y = (vval - mu) * rsqrtf(var + 1e-3f);

    float sq = sum8(y * y);
    if (valid && (tid & 7) == 0) lenb[o] = sqrtf(sq + 1e-6f);
    __syncthreads();

    if (tid == 0) {
        float s1 = 0.f, s2 = 0.f;
        for (int oo = 0; oo < O1; ++oo) { float t = lenb[oo]; s1 += t; s2 += t * t; }
        float m2 = s1 / 31.f;
        mv2[0] = m2;
        mv2[1] = rsqrtf(s2 / 31.f - m2 * m2 + 1e-3f);
    }
    __syncthreads();
    if (tid < O1)
        outp[(size_t)bs * O1 + tid] = (lenb[tid] - mv2[0]) * mv2[1];
}

// ---------------------------------------------------------------- launch
extern "C" void kernel_launch(void* const* d_in, const int* in_sizes, int n_in,
                              void* d_out, int out_size, void* d_ws, size_t ws_size,
                              hipStream_t stream) {
    const float* inputs = (const float*)d_in[0];
    const float* c0w1 = (const float*)d_in[1];
    const float* c0b1 = (const float*)d_in[2];
    const float* c0w2 = (const float*)d_in[3];
    const float* c0b2 = (const float*)d_in[4];
    const float* c1w1 = (const float*)d_in[5];
    const float* c1b1 = (const float*)d_in[6];
    const float* c1w2 = (const float*)d_in[7];
    const float* c1b2 = (const float*)d_in[8];
    const float* pw   = (const float*)d_in[9];
    const float* pb   = (const float*)d_in[10];
    const float* ew1  = (const float*)d_in[11];
    const float* eb1  = (const float*)d_in[12];
    const float* ew2  = (const float*)d_in[13];
    const float* eb2  = (const float*)d_in[14];
    const float* W0   = (const float*)d_in[15];
    const float* B0   = (const float*)d_in[16];
    const float* W1   = (const float*)d_in[17];
    const float* B1   = (const float*)d_in[18];
    const int* lens = (const int*)d_in[19];

    char* ws = (char*)d_ws;
    u16*   x1    = (u16*)(ws);                       // 41,943,040 B
    u16*   x2    = (u16*)(ws + 41943040);            // 10,485,760 B (bf16)
    float* proj  = (float*)(ws + 52428800);          //    524,288 B
    float* emb0  = (float*)(ws + 52953088);          //  4,194,304 B
    float* emb1  = (float*)(ws + 57147392);          //  4,194,304 B
    u16*   W0h   = (u16*)(ws + 61341696);            //    393,216 B (f16)
    u16*   W1h   = (u16*)(ws + 61734912);            //    380,928 B (f16)
    u16*   wt    = (u16*)(ws + 62115840);            //    147,456 B
    float* biasi = (float*)(ws + 62263296);          //        512 B (end ~62.3 MB)

    k_prep<<<(NW0 + 255) / 256, 256, 0, stream>>>(
        W0, W1, c1w1, c1b1, c1w2, c1b2, W0h, W1h, wt, biasi);
    k_conv0<<<(Bn * H1 * W1n * NF) / 256, 256, 0, stream>>>(
        inputs, c0w1, c0b1, c0w2, c0b2, lens, x1);
    k_conv1<<<640, 256, 0, stream>>>(x1, wt, biasi, lens, x2);
    k_proj<<<Bn * Sn, 256, 0, stream>>>(x2, pw, pb, proj);
    k_enc<<<Bn * Sn, 256, 0, stream>>>(proj, ew1, eb1, ew2, eb2, lens, emb0);
    k_caps0<<<Bn * Sn, 256, 0, stream>>>(emb0, W0h, B0, emb1);
    k_caps1<<<Bn * Sn, 256, 0, stream>>>(emb1, W1h, B1, (float*)d_out);
}

// Round 10
// 437.042 us; speedup vs baseline: 1.7672x; 1.0327x over previous
//
#include <hip/hip_runtime.h>

typedef unsigned short u16;
typedef unsigned int u32;
typedef short short8 __attribute__((ext_vector_type(8)));
typedef float f32x4 __attribute__((ext_vector_type(4)));
typedef _Float16 h2 __attribute__((ext_vector_type(2)));
typedef __fp16 fp16v2 __attribute__((ext_vector_type(2)));

#define DEV static __device__ __forceinline__

DEV float bf2f(u16 v) { return __uint_as_float((u32)v << 16); }
DEV u16 f2bf(float f) {
    u32 x = __float_as_uint(f);
    return (u16)((x + 0x7fffu + ((x >> 16) & 1u)) >> 16);  // RNE
}
DEV u16 f2h(float f) {
    union { _Float16 h; u16 u; } c; c.h = (_Float16)f; return c.u;
}
DEV u32 pack2h(float a, float b) {
#if __has_builtin(__builtin_amdgcn_cvt_pkrtz)
    union { fp16v2 h; u32 u; } c;
    c.h = __builtin_amdgcn_cvt_pkrtz(a, b);
    return c.u;
#else
    union { u32 u; _Float16 h[2]; } c;
    c.h[0] = (_Float16)a; c.h[1] = (_Float16)b; return c.u;
#endif
}
DEV h2 u2h(u32 x) { union { u32 u; h2 h; } c; c.u = x; return c.h; }
DEV u32 h2u(h2 v) { union { h2 h; u32 u; } c; c.h = v; return c.u; }

#if __has_builtin(__builtin_amdgcn_fdot2)
DEV float dot2(u32 a, u32 b, float c) {
    return __builtin_amdgcn_fdot2(u2h(a), u2h(b), c, false);
}
#else
DEV float dot2(u32 a, u32 b, float c) {
    h2 ha = u2h(a), hb = u2h(b);
    c = fmaf((float)ha[0], (float)hb[0], c);
    return fmaf((float)ha[1], (float)hb[1], c);
}
#endif

constexpr int Bn = 8, Tn = 2048, Fn = 80, NF = 64;
constexpr int H1 = 1024, W1n = 40;          // after conv0 (stride 2)
constexpr int Sn = 512,  W2n = 20;          // after conv1 (stride 2)
constexpr int PK = 1280;                    // 20*64
constexpr int I0 = 96;                      // 32 capsules * window 3
constexpr int O0 = 32;                      // conv capsules
constexpr int O1 = 31;                      // class capsules
constexpr int CPW = 52;                     // packed-c row stride (u32; 16B aligned)
constexpr int NW0 = I0 * O0 * 8 * 8;        // 196608
constexpr int NW1 = I0 * O1 * 8 * 8;        // 190464
constexpr int KC1 = 576;                    // conv1 GEMM K (9*64)

// ---------------------------------------------------------------- DPP helpers
template <int CTRL>
DEV float dpp_mov(float x) {
    return __int_as_float(__builtin_amdgcn_update_dpp(
        0, __float_as_int(x), CTRL, 0xF, 0xF, true));
}
template <int CTRL>
DEV u32 dppu(u32 x) {
    return (u32)__builtin_amdgcn_update_dpp(0, (int)x, CTRL, 0xF, 0xF, true);
}
DEV float sum8(float x) {
    x += dpp_mov<0xB1>(x);    // quad_perm xor1
    x += dpp_mov<0x4E>(x);    // quad_perm xor2
    x += dpp_mov<0x141>(x);   // row_half_mirror
    return x;
}
DEV u32 sum8h(u32 x) {        // packed f16 pair, 8-lane sum of both halves
    x = h2u(u2h(x) + u2h(dppu<0xB1>(x)));
    x = h2u(u2h(x) + u2h(dppu<0x4E>(x)));
    x = h2u(u2h(x) + u2h(dppu<0x141>(x)));
    return x;
}

// ---------------------------------------------------------------- block reduce (4 waves)
DEV float2 block_sum2(float a, float b, int tid, float* lds /*>=8 floats*/) {
    #pragma unroll
    for (int m = 1; m < 64; m <<= 1) {
        a += __shfl_xor(a, m);
        b += __shfl_xor(b, m);
    }
    int wid = tid >> 6;
    __syncthreads();
    if ((tid & 63) == 0) { lds[wid * 2] = a; lds[wid * 2 + 1] = b; }
    __syncthreads();
    float ra = lds[0] + lds[2] + lds[4] + lds[6];
    float rb = lds[1] + lds[3] + lds[5] + lds[7];
    return make_float2(ra, rb);
}

// ---------------------------------------------------------------- K0: prep
__global__ void __launch_bounds__(256) k_prep(
        const float* __restrict__ w0, const float* __restrict__ w1c,
        const float* __restrict__ cw1, const float* __restrict__ cb1,
        const float* __restrict__ cw2, const float* __restrict__ cb2,
        u16* __restrict__ w0h, u16* __restrict__ w1h,
        u16* __restrict__ wt, float* __restrict__ biasi) {
    int idx = blockIdx.x * 256 + threadIdx.x;
    if (idx < NW0) w0h[idx] = f2h(w0[idx]);
    if (idx < NW1) w1h[idx] = f2h(w1c[idx]);
    if (idx < 128 * KC1) {
        int n = idx / KC1, k = idx - n * KC1;
        int c = n >> 1, s = n & 1;
        const float* w = s ? cw2 : cw1;   // [3,3,64,64] flat: k*64 + c
        wt[idx] = f2bf(w[k * 64 + c]);
    }
    if (idx < 128) {
        int c = idx >> 1, s = idx & 1;
        biasi[idx] = (s ? cb2 : cb1)[c];
    }
}

// ---------------------------------------------------------------- K1: conv0 maxout
__global__ void __launch_bounds__(256) k_conv0(
        const float* __restrict__ in,
        const float* __restrict__ w1, const float* __restrict__ b1,
        const float* __restrict__ w2, const float* __restrict__ b2,
        const int* __restrict__ lens, u16* __restrict__ x1) {
    int idx = blockIdx.x * 256 + threadIdx.x;
    if (idx >= Bn * H1 * W1n * NF) return;
    int c = idx & 63;
    int rest = idx >> 6;
    int w = rest % W1n; rest /= W1n;
    int h = rest % H1;
    int b = rest / H1;
    float out = 0.f;
    int vl2 = (lens[b] + 1) >> 1;
    if (h < vl2) {
        float a1 = b1[c], a2 = b2[c];
        #pragma unroll
        for (int r = 0; r < 3; ++r) {
            int t = 2 * h + r;
            if (t < Tn) {
                #pragma unroll
                for (int q = 0; q < 3; ++q) {
                    int f = 2 * w + q;
                    if (f < Fn) {
                        float v = in[(b * Tn + t) * Fn + f];
                        int wi = (r * 3 + q) * 64 + c;
                        a1 = fmaf(v, w1[wi], a1);
                        a2 = fmaf(v, w2[wi], a2);
                    }
                }
            }
        }
        out = fmaxf(a1, a2);
    }
    x1[idx] = f2bf(out);
}

// ---------------------------------------------------------------- K2: conv1 via MFMA implicit GEMM
__global__ void __launch_bounds__(256) k_conv1(
        const u16* __restrict__ x1, const u16* __restrict__ wt,
        const float* __restrict__ biasi, const int* __restrict__ lens,
        u16* __restrict__ x2) {
    constexpr int LD = 40;
    __shared__ u16 Al[2][128 * LD];
    __shared__ u16 Bl[2][128 * LD];
    __shared__ float bs_lds[128];

    int tid = threadIdx.x;
    int m0 = blockIdx.x * 128;
    int b = m0 / 10240;
    int vl4 = (lens[b] + 3) >> 2;

    if (tid < 128) bs_lds[tid] = biasi[tid];

    int srow = tid >> 1;
    int shalf = tid & 1;
    int am = m0 + srow;
    int aw = am % 20;
    int ah = (am / 20) % 512;
    const u16* abase = x1 + (((size_t)b * 1024 + 2 * ah) * 40 + 2 * aw) * 64;
    const u16* bbase = wt + srow * KC1;

    const uint4 uz = make_uint4(0, 0, 0, 0);
    uint4 na0, na1, nb0, nb1;
    {
        const u16* ap = abase + shalf * 16;
        na0 = *(const uint4*)(ap);
        na1 = *(const uint4*)(ap + 8);
        const u16* bp = bbase + shalf * 16;
        nb0 = *(const uint4*)(bp);
        nb1 = *(const uint4*)(bp + 8);
    }
    {
        u16* awp = &Al[0][srow * LD + shalf * 16];
        *(uint4*)awp = na0; *(uint4*)(awp + 8) = na1;
        u16* bwp = &Bl[0][srow * LD + shalf * 16];
        *(uint4*)bwp = nb0; *(uint4*)(bwp + 8) = nb1;
    }
    __syncthreads();

    int lane = tid & 63;
    int wid = tid >> 6;
    int mw = wid & 1, nw = wid >> 1;
    int frow = lane & 15;
    int koff = (lane >> 4) * 8;

    f32x4 acc[4][4] = {};
    int buf = 0;

    #pragma unroll
    for (int kc = 0; kc < 18; ++kc) {
        if (kc < 17) {
            int kn = kc + 1;
            int rq = kn >> 1, ci0 = (kn & 1) * 32;
            int r = rq / 3, q = rq - 3 * r;
            bool v = (2 * ah + r < 1024) && (2 * aw + q < 40);
            const u16* ap = abase + (r * 40 + q) * 64 + ci0 + shalf * 16;
            na0 = v ? *(const uint4*)(ap) : uz;
            na1 = v ? *(const uint4*)(ap + 8) : uz;
            const u16* bp = bbase + kn * 32 + shalf * 16;
            nb0 = *(const uint4*)(bp);
            nb1 = *(const uint4*)(bp + 8);
        }
        const u16* Ar = &Al[buf][(mw * 64 + frow) * LD + koff];
        const u16* Br = &Bl[buf][(nw * 64 + frow) * LD + koff];
        short8 af[4], bfr[4];
        #pragma unroll
        for (int s = 0; s < 4; ++s) {
            af[s]  = *(const short8*)(Ar + s * 16 * LD);
            bfr[s] = *(const short8*)(Br + s * 16 * LD);
        }
        #pragma unroll
        for (int sm = 0; sm < 4; ++sm)
            #pragma unroll
            for (int sn = 0; sn < 4; ++sn)
                acc[sm][sn] = __builtin_amdgcn_mfma_f32_16x16x32_bf16(
                    af[sm], bfr[sn], acc[sm][sn], 0, 0, 0);
        if (kc < 17) {
            buf ^= 1;
            u16* awp = &Al[buf][srow * LD + shalf * 16];
            *(uint4*)awp = na0; *(uint4*)(awp + 8) = na1;
            u16* bwp = &Bl[buf][srow * LD + shalf * 16];
            *(uint4*)bwp = nb0; *(uint4*)(bwp + 8) = nb1;
            __syncthreads();
        }
    }

    int orow = (lane >> 4) * 4;
    int ncol = lane & 15;
    #pragma unroll
    for (int sm = 0; sm < 4; ++sm) {
        #pragma unroll
        for (int sn = 0; sn < 4; ++sn) {
            int np = nw * 64 + sn * 16 + ncol;
            float bia = bs_lds[np];
            #pragma unroll
            for (int r = 0; r < 4; ++r) {
                float v = acc[sm][sn][r] + bia;
                float o = fmaxf(v, dpp_mov<0xB1>(v));
                if (!(lane & 1)) {
                    int gm = m0 + mw * 64 + sm * 16 + orow + r;
                    int w = gm % 20;
                    int h = (gm / 20) % 512;
                    float res = (h >= vl4) ? 0.f : o;
                    x2[((size_t)(b * 512 + h) * 20 + w) * 64 + (np >> 1)] = f2bf(res);
                }
            }
        }
    }
}

// ---------------------------------------------------------------- K3a: projection
__global__ void __launch_bounds__(256) k_proj(
        const u16* __restrict__ x2, const float* __restrict__ pw,
        const float* __restrict__ pb, float* __restrict__ proj) {
    int bs = blockIdx.x;
    int tid = threadIdx.x;
    int o = tid & 31, part = tid >> 5;
    const u16* row = &x2[(size_t)bs * PK];
    float acc = 0.f;
    int k0 = part * 160;
    #pragma unroll 8
    for (int k = 0; k < 160; ++k)
        acc = fmaf(bf2f(row[k0 + k]), pw[(k0 + k) * 32 + o], acc);
    __shared__ float red[256];
    red[tid] = acc;
    __syncthreads();
    if (tid < 32) {
        float s = 0.f;
        #pragma unroll
        for (int p = 0; p < 8; ++p) s += red[p * 32 + tid];
        proj[bs * 32 + tid] = s + pb[tid];
    }
}

// ---------------------------------------------------------------- K3b: enc conv + mask + squash + LN
__global__ void __launch_bounds__(256) k_enc(
        const float* __restrict__ proj,
        const float* __restrict__ ew1, const float* __restrict__ eb1,
        const float* __restrict__ ew2, const float* __restrict__ eb2,
        const int* __restrict__ lens, float* __restrict__ emb0) {
    int bs = blockIdx.x;
    int s = bs & (Sn - 1);
    int b = bs >> 9;
    int tid = threadIdx.x;
    __shared__ float rows[3][32];
    __shared__ float red[8];
    if (tid < 96) {
        int r = tid >> 5, n = tid & 31;
        int sr = s - 1 + r;
        rows[r][n] = (sr >= 0 && sr < Sn) ? proj[(b * Sn + sr) * 32 + n] : 0.f;
    }
    __syncthreads();

    int n = tid >> 3, d = tid & 7;
    float a1 = eb1[d], a2 = eb2[d];
    #pragma unroll
    for (int r = 0; r < 3; ++r) {
        #pragma unroll
        for (int q = 0; q < 3; ++q) {
            int nn = n - 1 + q;
            if (nn >= 0 && nn < 32) {
                float v = rows[r][nn];
                int wi = (r * 3 + q) * 8 + d;
                a1 = fmaf(v, ew1[wi], a1);
                a2 = fmaf(v, ew2[wi], a2);
            }
        }
    }
    float x = fmaxf(a1, a2);
    int vl4 = (lens[b] + 3) >> 2;
    if (s >= vl4) x = 0.f;

    float sq = sum8(x * x);
    x = x * (sq / (1.f + sq) * rsqrtf(sq + 1e-6f));

    float2 ss = block_sum2(x, x * x, tid, red);
    float mu = ss.x * (1.f / 256.f);
    float var = ss.y * (1.f / 256.f) - mu * mu;
    emb0[bs * 256 + tid] = (x - mu) * rsqrtf(var + 1e-3f);
}

// ---------------------------------------------------------------- K4: caps layer 0 (G=2 s-blocked, packed-f16 u)
__global__ void __launch_bounds__(256, 3) k_caps0(
        const float* __restrict__ embin, const u16* __restrict__ W0,
        const float* __restrict__ B0, float* __restrict__ embout) {
    int pb2 = blockIdx.x;
    int b = pb2 >> 8;
    int s0 = (pb2 & 255) << 1;            // handles s0, s0+1
    int tid = threadIdx.x;
    int o = tid >> 3;

    __shared__ __align__(16) u32 win2[2][I0 * 4];
    __shared__ float blog[2][I0 * 33];
    __shared__ __align__(16) u32 cpk[2][O0 * CPW];
    __shared__ float red[8];
    u16* cph0 = (u16*)cpk[0];
    u16* cph1 = (u16*)cpk[1];

    for (int idx = tid; idx < 2 * I0 * 4; idx += 256) {
        int g = idx >= I0 * 4;
        int lidx = idx - g * I0 * 4;
        int i = lidx >> 2, kk = lidx & 3;
        int sr = s0 + g + (i >> 5) - 1;
        float a = 0.f, bv = 0.f;
        if (sr >= 0 && sr < Sn) {
            const float* p = &embin[(b * Sn + sr) * 256 + (i & 31) * 8 + kk * 2];
            a = p[0]; bv = p[1];
        }
        win2[g][lidx] = pack2h(a, bv);
    }
    for (int i = tid; i < 2 * I0 * 33; i += 256) blog[0][i] = 0.f;  // covers both
    __syncthreads();

    // u_hat for both s, sharing W/B loads
    u32 u_pk0[48], u_pk1[48];
    {
        const uint4* Wv = (const uint4*)W0;
        const uint4* wl0 = (const uint4*)win2[0];
        const uint4* wl1 = (const uint4*)win2[1];
        #pragma unroll
        for (int ii = 0; ii < 48; ++ii) {
            int i0 = 2 * ii, i1 = 2 * ii + 1;
            uint4 wv0 = Wv[i0 * 256 + tid];
            uint4 wv1 = Wv[i1 * 256 + tid];
            float bb0 = B0[i0 * 256 + tid];
            float bb1 = B0[i1 * 256 + tid];
            uint4 wa0 = wl0[i0], wa1 = wl0[i1];
            float a0 = bb0, a1 = bb1;
            a0 = dot2(wv0.x, wa0.x, a0);
            a0 = dot2(wv0.y, wa0.y, a0);
            a0 = dot2(wv0.z, wa0.z, a0);
            a0 = dot2(wv0.w, wa0.w, a0);
            a1 = dot2(wv1.x, wa1.x, a1);
            a1 = dot2(wv1.y, wa1.y, a1);
            a1 = dot2(wv1.z, wa1.z, a1);
            a1 = dot2(wv1.w, wa1.w, a1);
            u_pk0[ii] = pack2h(a0, a1);
            uint4 wb0 = wl1[i0], wb1 = wl1[i1];
            a0 = bb0; a1 = bb1;
            a0 = dot2(wv0.x, wb0.x, a0);
            a0 = dot2(wv0.y, wb0.y, a0);
            a0 = dot2(wv0.z, wb0.z, a0);
            a0 = dot2(wv0.w, wb0.w, a0);
            a1 = dot2(wv1.x, wb1.x, a1);
            a1 = dot2(wv1.y, wb1.y, a1);
            a1 = dot2(wv1.z, wb1.z, a1);
            a1 = dot2(wv1.w, wb1.w, a1);
            u_pk1[ii] = pack2h(a0, a1);
        }
    }

    float vv0 = 0.f, vv1 = 0.f;
    for (int it = 0; it < 3; ++it) {
        if (tid < 192) {
            int i = tid >> 1, hf = tid & 1;
            int o0 = hf * 16;
            #pragma unroll
            for (int g = 0; g < 2; ++g) {
                float ex[16];
                float ssum = 0.f;
                #pragma unroll
                for (int j = 0; j < 16; ++j) {
                    ex[j] = __expf(blog[g][i * 33 + o0 + j]);
                    ssum += ex[j];
                }
                ssum += dpp_mov<0xB1>(ssum);
                float inv = __builtin_amdgcn_rcpf(ssum);
                u16* cc = g ? cph1 : cph0;
                #pragma unroll
                for (int j = 0; j < 16; ++j)
                    cc[(o0 + j) * (CPW * 2) + i] = f2h(ex[j] * inv);
            }
        }
        __syncthreads();
        {
            float sv0 = 0.f, sv1 = 0.f;
            const uint4* cr0 = (const uint4*)&cpk[0][o * CPW];
            const uint4* cr1 = (const uint4*)&cpk[1][o * CPW];
            #pragma unroll
            for (int q4 = 0; q4 < 12; ++q4) {
                uint4 c0 = cr0[q4], c1 = cr1[q4];
                sv0 = dot2(u_pk0[q4 * 4 + 0], c0.x, sv0);
                sv0 = dot2(u_pk0[q4 * 4 + 1], c0.y, sv0);
                sv0 = dot2(u_pk0[q4 * 4 + 2], c0.z, sv0);
                sv0 = dot2(u_pk0[q4 * 4 + 3], c0.w, sv0);
                sv1 = dot2(u_pk1[q4 * 4 + 0], c1.x, sv1);
                sv1 = dot2(u_pk1[q4 * 4 + 1], c1.y, sv1);
                sv1 = dot2(u_pk1[q4 * 4 + 2], c1.z, sv1);
                sv1 = dot2(u_pk1[q4 * 4 + 3], c1.w, sv1);
            }
            float sq0 = sum8(sv0 * sv0);
            float sq1 = sum8(sv1 * sv1);
            vv0 = sv0 * (sq0 / (1.f + sq0) * rsqrtf(sq0 + 1e-6f));
            vv1 = sv1 * (sq1 / (1.f + sq1) * rsqrtf(sq1 + 1e-6f));
        }
        if (it < 2) {
            u32 va = pack2h(vv0, vv0), vb = pack2h(vv1, vv1);
            #pragma unroll
            for (int ii = 0; ii < 48; ++ii) {
                u32 p0 = sum8h(h2u(u2h(u_pk0[ii]) * u2h(va)));
                u32 p1 = sum8h(h2u(u2h(u_pk1[ii]) * u2h(vb)));
                if ((tid & 7) == 0) {
                    h2 q0 = u2h(p0), q1 = u2h(p1);
                    blog[0][(2 * ii) * 33 + o]     += (float)q0[0];
                    blog[0][(2 * ii + 1) * 33 + o] += (float)q0[1];
                    blog[1][(2 * ii) * 33 + o]     += (float)q1[0];
                    blog[1][(2 * ii + 1) * 33 + o] += (float)q1[1];
                }
            }
            __syncthreads();
        }
    }

    // layernorm per s and write
    float2 ss = block_sum2(vv0, vv0 * vv0, tid, red);
    float mu = ss.x * (1.f / 256.f);
    float var = ss.y * (1.f / 256.f) - mu * mu;
    embout[(b * Sn + s0) * 256 + tid] = (vv0 - mu) * rsqrtf(var + 1e-3f);
    ss = block_sum2(vv1, vv1 * vv1, tid, red);
    mu = ss.x * (1.f / 256.f);
    var = ss.y * (1.f / 256.f) - mu * mu;
    embout[(b * Sn + s0 + 1) * 256 + tid] = (vv1 - mu) * rsqrtf(var + 1e-3f);
}

// ---------------------------------------------------------------- K5: caps layer 1 + epilogue (G=2)
__global__ void __launch_bounds__(256, 3) k_caps1(
        const float* __restrict__ embin, const u16* __restrict__ W1,
        const float* __restrict__ B1, float* __restrict__ outp) {
    int pb2 = blockIdx.x;
    int b = pb2 >> 8;
    int s0 = (pb2 & 255) << 1;
    int tid = threadIdx.x;
    int o = tid >> 3, d = tid & 7;
    bool valid = (o < O1);
    int oc = valid ? o : (O1 - 1);
    int ocd = oc * 8 + d;

    __shared__ __align__(16) u32 win2[2][I0 * 4];
    __shared__ float blog[2][I0 * 33];
    __shared__ __align__(16) u32 cpk[2][O1 * CPW];
    __shared__ float red[8];
    __shared__ float lenb[2][O1];
    __shared__ float mv2[4];
    u16* cph0 = (u16*)cpk[0];
    u16* cph1 = (u16*)cpk[1];

    for (int idx = tid; idx < 2 * I0 * 4; idx += 256) {
        int g = idx >= I0 * 4;
        int lidx = idx - g * I0 * 4;
        int i = lidx >> 2, kk = lidx & 3;
        int sr = s0 + g + (i >> 5) - 1;
        float a = 0.f, bv = 0.f;
        if (sr >= 0 && sr < Sn) {
            const float* p = &embin[(b * Sn + sr) * 256 + (i & 31) * 8 + kk * 2];
            a = p[0]; bv = p[1];
        }
        win2[g][lidx] = pack2h(a, bv);
    }
    for (int i = tid; i < 2 * I0 * 33; i += 256) blog[0][i] = 0.f;
    for (int i = tid; i < CPW; i += 256) { cpk[0][i] = 0; cpk[1][i] = 0; }  // class-0 rows
    __syncthreads();

    u32 u_pk0[48], u_pk1[48];
    {
        const uint4* Wv = (const uint4*)W1;
        const uint4* wl0 = (const uint4*)win2[0];
        const uint4* wl1 = (const uint4*)win2[1];
        #pragma unroll
        for (int ii = 0; ii < 48; ++ii) {
            int i0 = 2 * ii, i1 = 2 * ii + 1;
            uint4 wv0 = Wv[i0 * 248 + ocd];
            uint4 wv1 = Wv[i1 * 248 + ocd];
            float bb0 = B1[i0 * 248 + ocd];
            float bb1 = B1[i1 * 248 + ocd];
            uint4 wa0 = wl0[i0], wa1 = wl0[i1];
            float a0 = bb0, a1 = bb1;
            a0 = dot2(wv0.x, wa0.x, a0);
            a0 = dot2(wv0.y, wa0.y, a0);
            a0 = dot2(wv0.z, wa0.z, a0);
            a0 = dot2(wv0.w, wa0.w, a0);
            a1 = dot2(wv1.x, wa1.x, a1);
            a1 = dot2(wv1.y, wa1.y, a1);
            a1 = dot2(wv1.z, wa1.z, a1);
            a1 = dot2(wv1.w, wa1.w, a1);
            u_pk0[ii] = pack2h(a0, a1);
            uint4 wb0 = wl1[i0], wb1 = wl1[i1];
            a0 = bb0; a1 = bb1;
            a0 = dot2(wv0.x, wb0.x, a0);
            a0 = dot2(wv0.y, wb0.y, a0);
            a0 = dot2(wv0.z, wb0.z, a0);
            a0 = dot2(wv0.w, wb0.w, a0);
            a1 = dot2(wv1.x, wb1.x, a1);
            a1 = dot2(wv1.y, wb1.y, a1);
            a1 = dot2(wv1.z, wb1.z, a1);
            a1 = dot2(wv1.w, wb1.w, a1);
            u_pk1[ii] = pack2h(a0, a1);
        }
    }

    float vv0 = 0.f, vv1 = 0.f;
    for (int it = 0; it < 3; ++it) {
        if (tid < 192) {
            int i = tid >> 1, hf = tid & 1;
            int lo = hf ? 16 : 1;
            #pragma unroll
            for (int g = 0; g < 2; ++g) {
                float ex[15];
                float ssum = 0.f;
                #pragma unroll
                for (int j = 0; j < 15; ++j) {
                    ex[j] = __expf(blog[g][i * 33 + lo + j]);
                    ssum += ex[j];
                }
                ssum += dpp_mov<0xB1>(ssum);
                float inv = __builtin_amdgcn_rcpf(ssum);
                u16* cc = g ? cph1 : cph0;
                #pragma unroll
                for (int j = 0; j < 15; ++j)
                    cc[(lo + j) * (CPW * 2) + i] = f2h(ex[j] * inv);
            }
        }
        __syncthreads();
        {
            float sv0 = 0.f, sv1 = 0.f;
            const uint4* cr0 = (const uint4*)&cpk[0][oc * CPW];
            const uint4* cr1 = (const uint4*)&cpk[1][oc * CPW];
            #pragma unroll
            for (int q4 = 0; q4 < 12; ++q4) {
                uint4 c0 = cr0[q4], c1 = cr1[q4];
                sv0 = dot2(u_pk0[q4 * 4 + 0], c0.x, sv0);
                sv0 = dot2(u_pk0[q4 * 4 + 1], c0.y, sv0);
                sv0 = dot2(u_pk0[q4 * 4 + 2], c0.z, sv0);
                sv0 = dot2(u_pk0[q4 * 4 + 3], c0.w, sv0);
                sv1 = dot2(u_pk1[q4 * 4 + 0], c1.x, sv1);
                sv1 = dot2(u_pk1[q4 * 4 + 1], c1.y, sv1);
                sv1 = dot2(u_pk1[q4 * 4 + 2], c1.z, sv1);
                sv1 = dot2(u_pk1[q4 * 4 + 3], c1.w, sv1);
            }
            float sq0 = sum8(sv0 * sv0);
            float sq1 = sum8(sv1 * sv1);
            vv0 = sv0 * (sq0 / (1.f + sq0) * rsqrtf(sq0 + 1e-6f));
            vv1 = sv1 * (sq1 / (1.f + sq1) * rsqrtf(sq1 + 1e-6f));
            if (!valid) { vv0 = 0.f; vv1 = 0.f; }
        }
        if (it < 2) {
            u32 va = pack2h(vv0, vv0), vb = pack2h(vv1, vv1);
            #pragma unroll
            for (int ii = 0; ii < 48; ++ii) {
                u32 p0 = sum8h(h2u(u2h(u_pk0[ii]) * u2h(va)));
                u32 p1 = sum8h(h2u(u2h(u_pk1[ii]) * u2h(vb)));
                if ((tid & 7) == 0 && valid) {
                    h2 q0 = u2h(p0), q1 = u2h(p1);
                    blog[0][(2 * ii) * 33 + o]     += (float)q0[0];
                    blog[0][(2 * ii + 1) * 33 + o] += (float)q0[1];
                    blog[1][(2 * ii) * 33 + o]     += (float)q1[0];
                    blog[1][(2 * ii + 1) * 33 + o] += (float)q1[1];
                }
            }
            __syncthreads();
        }
    }

    // LN(248) + lengths per s
    float2 ss = block_sum2(vv0, vv0 * vv0, tid, red);
    float mu = ss.x * (1.f / 248.f);
    float var = ss.y * (1.f / 248.f) - mu * mu;
    float y0 = (vv0 - mu) * rsqrtf(var + 1e-3f);
    ss = block_sum2(vv1, vv1 * vv1, tid, red);
    mu = ss.x * (1.f / 248.f);
    var = ss.y * (1.f / 248.f) - mu * mu;
    float y1 = (vv1 - mu) * rsqrtf(var + 1e-3f);

    float sq0 = sum8(y0 * y0);
    float sq1 = sum8(y1 * y1);
    if (valid && (tid & 7) == 0) {
        lenb[0][o] = sqrtf(sq0 + 1e-6f);
        lenb[1][o] = sqrtf(sq1 + 1e-6f);
    }
    __syncthreads();

    if (tid < 2) {
        float s1 = 0.f, s2 = 0.f;
        for (int oo = 0; oo < O1; ++oo) { float t = lenb[tid][oo]; s1 += t; s2 += t * t; }
        float m2 = s1 / 31.f;
        mv2[tid * 2] = m2;
        mv2[tid * 2 + 1] = rsqrtf(s2 / 31.f - m2 * m2 + 1e-3f);
    }
    __syncthreads();
    if (tid < O1) {
        outp[(size_t)(b * Sn + s0) * O1 + tid] = (lenb[0][tid] - mv2[0]) * mv2[1];
        outp[(size_t)(b * Sn + s0 + 1) * O1 + tid] = (lenb[1][tid] - mv2[2]) * mv2[3];
    }
}

// ---------------------------------------------------------------- launch
extern "C" void kernel_launch(void* const* d_in, const int* in_sizes, int n_in,
                              void* d_out, int out_size, void* d_ws, size_t ws_size,
                              hipStream_t stream) {
    const float* inputs = (const float*)d_in[0];
    const float* c0w1 = (const float*)d_in[1];
    const float* c0b1 = (const float*)d_in[2];
    const float* c0w2 = (const float*)d_in[3];
    const float* c0b2 = (const float*)d_in[4];
    const float* c1w1 = (const float*)d_in[5];
    const float* c1b1 = (const float*)d_in[6];
    const float* c1w2 = (const float*)d_in[7];
    const float* c1b2 = (const float*)d_in[8];
    const float* pw   = (const float*)d_in[9];
    const float* pb   = (const float*)d_in[10];
    const float* ew1  = (const float*)d_in[11];
    const float* eb1  = (const float*)d_in[12];
    const float* ew2  = (const float*)d_in[13];
    const float* eb2  = (const float*)d_in[14];
    const float* W0   = (const float*)d_in[15];
    const float* B0   = (const float*)d_in[16];
    const float* W1   = (const float*)d_in[17];
    const float* B1   = (const float*)d_in[18];
    const int* lens = (const int*)d_in[19];

    char* ws = (char*)d_ws;
    u16*   x1    = (u16*)(ws);                       // 41,943,040 B
    u16*   x2    = (u16*)(ws + 41943040);            // 10,485,760 B (bf16)
    float* proj  = (float*)(ws + 52428800);          //    524,288 B
    float* emb0  = (float*)(ws + 52953088);          //  4,194,304 B
    float* emb1  = (float*)(ws + 57147392);          //  4,194,304 B
    u16*   W0h   = (u16*)(ws + 61341696);            //    393,216 B (f16)
    u16*   W1h   = (u16*)(ws + 61734912);            //    380,928 B (f16)
    u16*   wt    = (u16*)(ws + 62115840);            //    147,456 B
    float* biasi = (float*)(ws + 62263296);          //        512 B (end ~62.3 MB)

    k_prep<<<(NW0 + 255) / 256, 256, 0, stream>>>(
        W0, W1, c1w1, c1b1, c1w2, c1b2, W0h, W1h, wt, biasi);
    k_conv0<<<(Bn * H1 * W1n * NF) / 256, 256, 0, stream>>>(
        inputs, c0w1, c0b1, c0w2, c0b2, lens, x1);
    k_conv1<<<640, 256, 0, stream>>>(x1, wt, biasi, lens, x2);
    k_proj<<<Bn * Sn, 256, 0, stream>>>(x2, pw, pb, proj);
    k_enc<<<Bn * Sn, 256, 0, stream>>>(proj, ew1, eb1, ew2, eb2, lens, emb0);
    k_caps0<<<Bn * Sn / 2, 256, 0, stream>>>(emb0, W0h, B0, emb1);
    k_caps1<<<Bn * Sn / 2, 256, 0, stream>>>(emb1, W1h, B1, (float*)d_out);
}

// Round 11
// 351.690 us; speedup vs baseline: 2.1960x; 1.2427x over previous
//
#include <hip/hip_runtime.h>

typedef unsigned short u16;
typedef unsigned int u32;
typedef short short8 __attribute__((ext_vector_type(8)));
typedef float f32x4 __attribute__((ext_vector_type(4)));
typedef _Float16 h2 __attribute__((ext_vector_type(2)));
typedef __fp16 fp16v2 __attribute__((ext_vector_type(2)));

#define DEV static __device__ __forceinline__

DEV float bf2f(u16 v) { return __uint_as_float((u32)v << 16); }
DEV u16 f2bf(float f) {
    u32 x = __float_as_uint(f);
    return (u16)((x + 0x7fffu + ((x >> 16) & 1u)) >> 16);  // RNE
}
DEV u16 f2h(float f) {
    union { _Float16 h; u16 u; } c; c.h = (_Float16)f; return c.u;
}
DEV u32 pack2h(float a, float b) {
#if __has_builtin(__builtin_amdgcn_cvt_pkrtz)
    union { fp16v2 h; u32 u; } c;
    c.h = __builtin_amdgcn_cvt_pkrtz(a, b);
    return c.u;
#else
    union { u32 u; _Float16 h[2]; } c;
    c.h[0] = (_Float16)a; c.h[1] = (_Float16)b; return c.u;
#endif
}
DEV h2 u2h(u32 x) { union { u32 u; h2 h; } c; c.u = x; return c.h; }
DEV u32 h2u(h2 v) { union { h2 h; u32 u; } c; c.h = v; return c.u; }

#if __has_builtin(__builtin_amdgcn_fdot2)
DEV float dot2(u32 a, u32 b, float c) {
    return __builtin_amdgcn_fdot2(u2h(a), u2h(b), c, false);
}
#else
DEV float dot2(u32 a, u32 b, float c) {
    h2 ha = u2h(a), hb = u2h(b);
    c = fmaf((float)ha[0], (float)hb[0], c);
    return fmaf((float)ha[1], (float)hb[1], c);
}
#endif

constexpr int Bn = 8, Tn = 2048, Fn = 80, NF = 64;
constexpr int H1 = 1024, W1n = 40;          // after conv0 (stride 2)
constexpr int Sn = 512,  W2n = 20;          // after conv1 (stride 2)
constexpr int PK = 1280;                    // 20*64
constexpr int I0 = 96;                      // 32 capsules * window 3
constexpr int O0 = 32;                      // conv capsules
constexpr int O1 = 31;                      // class capsules
constexpr int CPW = 52;                     // packed-c row stride (u32; 16B aligned)
constexpr int NW0 = I0 * O0 * 8 * 8;        // 196608
constexpr int NW1 = I0 * O1 * 8 * 8;        // 190464
constexpr int KC1 = 576;                    // conv1 GEMM K (9*64)

// ---------------------------------------------------------------- DPP helpers
template <int CTRL>
DEV float dpp_mov(float x) {
    return __int_as_float(__builtin_amdgcn_update_dpp(
        0, __float_as_int(x), CTRL, 0xF, 0xF, true));
}
template <int CTRL>
DEV u32 dppu(u32 x) {
    return (u32)__builtin_amdgcn_update_dpp(0, (int)x, CTRL, 0xF, 0xF, true);
}
DEV float sum8(float x) {
    x += dpp_mov<0xB1>(x);    // quad_perm xor1
    x += dpp_mov<0x4E>(x);    // quad_perm xor2
    x += dpp_mov<0x141>(x);   // row_half_mirror
    return x;
}
DEV u32 sum8h(u32 x) {        // packed f16 pair, 8-lane sum of both halves
    x = h2u(u2h(x) + u2h(dppu<0xB1>(x)));
    x = h2u(u2h(x) + u2h(dppu<0x4E>(x)));
    x = h2u(u2h(x) + u2h(dppu<0x141>(x)));
    return x;
}

// ---------------------------------------------------------------- block reduce (4 waves)
DEV float2 block_sum2(float a, float b, int tid, float* lds /*>=8 floats*/) {
    #pragma unroll
    for (int m = 1; m < 64; m <<= 1) {
        a += __shfl_xor(a, m);
        b += __shfl_xor(b, m);
    }
    int wid = tid >> 6;
    __syncthreads();
    if ((tid & 63) == 0) { lds[wid * 2] = a; lds[wid * 2 + 1] = b; }
    __syncthreads();
    float ra = lds[0] + lds[2] + lds[4] + lds[6];
    float rb = lds[1] + lds[3] + lds[5] + lds[7];
    return make_float2(ra, rb);
}

// ---------------------------------------------------------------- K0: prep
__global__ void __launch_bounds__(256) k_prep(
        const float* __restrict__ w0, const float* __restrict__ w1c,
        const float* __restrict__ cw1, const float* __restrict__ cb1,
        const float* __restrict__ cw2, const float* __restrict__ cb2,
        u16* __restrict__ w0h, u16* __restrict__ w1h,
        u16* __restrict__ wt, float* __restrict__ biasi) {
    int idx = blockIdx.x * 256 + threadIdx.x;
    if (idx < NW0) w0h[idx] = f2h(w0[idx]);
    if (idx < NW1) w1h[idx] = f2h(w1c[idx]);
    if (idx < 128 * KC1) {
        int n = idx / KC1, k = idx - n * KC1;
        int c = n >> 1, s = n & 1;
        const float* w = s ? cw2 : cw1;   // [3,3,64,64] flat: k*64 + c
        wt[idx] = f2bf(w[k * 64 + c]);
    }
    if (idx < 128) {
        int c = idx >> 1, s = idx & 1;
        biasi[idx] = (s ? cb2 : cb1)[c];
    }
}

// ---------------------------------------------------------------- K1: conv0 maxout (LDS-staged, 10 out/thread)
// block = (b,h); thread = (wq=tid/64, c=tid%64); outputs w = wq*10..wq*10+9
__global__ void __launch_bounds__(256) k_conv0(
        const float* __restrict__ in,
        const float* __restrict__ w1, const float* __restrict__ b1,
        const float* __restrict__ w2, const float* __restrict__ b2,
        const int* __restrict__ lens, u16* __restrict__ x1) {
    __shared__ float srow[3][82];   // f=80,81 stay 0 -> no f-bound check in loop
    int blk = blockIdx.x;
    int h = blk & (H1 - 1);
    int b = blk >> 10;
    int tid = threadIdx.x;

    for (int idx = tid; idx < 3 * 82; idx += 256) {
        int r = idx / 82, f = idx - r * 82;
        int t = 2 * h + r;
        float v = 0.f;
        if (t < Tn && f < Fn) v = in[(b * Tn + t) * Fn + f];
        srow[r][f] = v;
    }
    __syncthreads();

    int c = tid & 63;
    int wq = tid >> 6;
    float wr1[9], wr2[9];
    #pragma unroll
    for (int j = 0; j < 9; ++j) {
        wr1[j] = w1[j * 64 + c];
        wr2[j] = w2[j * 64 + c];
    }
    float bb1 = b1[c], bb2 = b2[c];
    int vl2 = (lens[b] + 1) >> 1;
    bool masked = (h >= vl2);

    u16* outbase = x1 + ((size_t)(b * H1 + h) * W1n) * 64 + c;
    #pragma unroll
    for (int p = 0; p < 10; ++p) {
        int w = wq * 10 + p;
        float a1 = bb1, a2 = bb2;
        #pragma unroll
        for (int r = 0; r < 3; ++r) {
            #pragma unroll
            for (int q = 0; q < 3; ++q) {
                float v = srow[r][2 * w + q];   // wave-uniform broadcast
                a1 = fmaf(v, wr1[r * 3 + q], a1);
                a2 = fmaf(v, wr2[r * 3 + q], a2);
            }
        }
        float out = masked ? 0.f : fmaxf(a1, a2);
        outbase[w * 64] = f2bf(out);
    }
}

// ---------------------------------------------------------------- K2: conv1 via MFMA implicit GEMM
__global__ void __launch_bounds__(256) k_conv1(
        const u16* __restrict__ x1, const u16* __restrict__ wt,
        const float* __restrict__ biasi, const int* __restrict__ lens,
        u16* __restrict__ x2) {
    constexpr int LD = 40;
    __shared__ u16 Al[2][128 * LD];
    __shared__ u16 Bl[2][128 * LD];
    __shared__ float bs_lds[128];

    int tid = threadIdx.x;
    int m0 = blockIdx.x * 128;
    int b = m0 / 10240;
    int vl4 = (lens[b] + 3) >> 2;

    if (tid < 128) bs_lds[tid] = biasi[tid];

    int srow = tid >> 1;
    int shalf = tid & 1;
    int am = m0 + srow;
    int aw = am % 20;
    int ah = (am / 20) % 512;
    const u16* abase = x1 + (((size_t)b * 1024 + 2 * ah) * 40 + 2 * aw) * 64;
    const u16* bbase = wt + srow * KC1;

    const uint4 uz = make_uint4(0, 0, 0, 0);
    uint4 na0, na1, nb0, nb1;
    {
        const u16* ap = abase + shalf * 16;
        na0 = *(const uint4*)(ap);
        na1 = *(const uint4*)(ap + 8);
        const u16* bp = bbase + shalf * 16;
        nb0 = *(const uint4*)(bp);
        nb1 = *(const uint4*)(bp + 8);
    }
    {
        u16* awp = &Al[0][srow * LD + shalf * 16];
        *(uint4*)awp = na0; *(uint4*)(awp + 8) = na1;
        u16* bwp = &Bl[0][srow * LD + shalf * 16];
        *(uint4*)bwp = nb0; *(uint4*)(bwp + 8) = nb1;
    }
    __syncthreads();

    int lane = tid & 63;
    int wid = tid >> 6;
    int mw = wid & 1, nw = wid >> 1;
    int frow = lane & 15;
    int koff = (lane >> 4) * 8;

    f32x4 acc[4][4] = {};
    int buf = 0;

    #pragma unroll
    for (int kc = 0; kc < 18; ++kc) {
        if (kc < 17) {
            int kn = kc + 1;
            int rq = kn >> 1, ci0 = (kn & 1) * 32;
            int r = rq / 3, q = rq - 3 * r;
            bool v = (2 * ah + r < 1024) && (2 * aw + q < 40);
            const u16* ap = abase + (r * 40 + q) * 64 + ci0 + shalf * 16;
            na0 = v ? *(const uint4*)(ap) : uz;
            na1 = v ? *(const uint4*)(ap + 8) : uz;
            const u16* bp = bbase + kn * 32 + shalf * 16;
            nb0 = *(const uint4*)(bp);
            nb1 = *(const uint4*)(bp + 8);
        }
        const u16* Ar = &Al[buf][(mw * 64 + frow) * LD + koff];
        const u16* Br = &Bl[buf][(nw * 64 + frow) * LD + koff];
        short8 af[4], bfr[4];
        #pragma unroll
        for (int s = 0; s < 4; ++s) {
            af[s]  = *(const short8*)(Ar + s * 16 * LD);
            bfr[s] = *(const short8*)(Br + s * 16 * LD);
        }
        #pragma unroll
        for (int sm = 0; sm < 4; ++sm)
            #pragma unroll
            for (int sn = 0; sn < 4; ++sn)
                acc[sm][sn] = __builtin_amdgcn_mfma_f32_16x16x32_bf16(
                    af[sm], bfr[sn], acc[sm][sn], 0, 0, 0);
        if (kc < 17) {
            buf ^= 1;
            u16* awp = &Al[buf][srow * LD + shalf * 16];
            *(uint4*)awp = na0; *(uint4*)(awp + 8) = na1;
            u16* bwp = &Bl[buf][srow * LD + shalf * 16];
            *(uint4*)bwp = nb0; *(uint4*)(bwp + 8) = nb1;
            __syncthreads();
        }
    }

    int orow = (lane >> 4) * 4;
    int ncol = lane & 15;
    #pragma unroll
    for (int sm = 0; sm < 4; ++sm) {
        #pragma unroll
        for (int sn = 0; sn < 4; ++sn) {
            int np = nw * 64 + sn * 16 + ncol;
            float bia = bs_lds[np];
            #pragma unroll
            for (int r = 0; r < 4; ++r) {
                float v = acc[sm][sn][r] + bia;
                float o = fmaxf(v, dpp_mov<0xB1>(v));
                if (!(lane & 1)) {
                    int gm = m0 + mw * 64 + sm * 16 + orow + r;
                    int w = gm % 20;
                    int h = (gm / 20) % 512;
                    float res = (h >= vl4) ? 0.f : o;
                    x2[((size_t)(b * 512 + h) * 20 + w) * 64 + (np >> 1)] = f2bf(res);
                }
            }
        }
    }
}

// ---------------------------------------------------------------- K3a: projection
__global__ void __launch_bounds__(256) k_proj(
        const u16* __restrict__ x2, const float* __restrict__ pw,
        const float* __restrict__ pb, float* __restrict__ proj) {
    int bs = blockIdx.x;
    int tid = threadIdx.x;
    int o = tid & 31, part = tid >> 5;
    const u16* row = &x2[(size_t)bs * PK];
    float acc = 0.f;
    int k0 = part * 160;
    #pragma unroll 8
    for (int k = 0; k < 160; ++k)
        acc = fmaf(bf2f(row[k0 + k]), pw[(k0 + k) * 32 + o], acc);
    __shared__ float red[256];
    red[tid] = acc;
    __syncthreads();
    if (tid < 32) {
        float s = 0.f;
        #pragma unroll
        for (int p = 0; p < 8; ++p) s += red[p * 32 + tid];
        proj[bs * 32 + tid] = s + pb[tid];
    }
}

// ---------------------------------------------------------------- K3b: enc conv + mask + squash + LN
__global__ void __launch_bounds__(256) k_enc(
        const float* __restrict__ proj,
        const float* __restrict__ ew1, const float* __restrict__ eb1,
        const float* __restrict__ ew2, const float* __restrict__ eb2,
        const int* __restrict__ lens, float* __restrict__ emb0) {
    int bs = blockIdx.x;
    int s = bs & (Sn - 1);
    int b = bs >> 9;
    int tid = threadIdx.x;
    __shared__ float rows[3][32];
    __shared__ float red[8];
    if (tid < 96) {
        int r = tid >> 5, n = tid & 31;
        int sr = s - 1 + r;
        rows[r][n] = (sr >= 0 && sr < Sn) ? proj[(b * Sn + sr) * 32 + n] : 0.f;
    }
    __syncthreads();

    int n = tid >> 3, d = tid & 7;
    float a1 = eb1[d], a2 = eb2[d];
    #pragma unroll
    for (int r = 0; r < 3; ++r) {
        #pragma unroll
        for (int q = 0; q < 3; ++q) {
            int nn = n - 1 + q;
            if (nn >= 0 && nn < 32) {
                float v = rows[r][nn];
                int wi = (r * 3 + q) * 8 + d;
                a1 = fmaf(v, ew1[wi], a1);
                a2 = fmaf(v, ew2[wi], a2);
            }
        }
    }
    float x = fmaxf(a1, a2);
    int vl4 = (lens[b] + 3) >> 2;
    if (s >= vl4) x = 0.f;

    float sq = sum8(x * x);
    x = x * (sq / (1.f + sq) * rsqrtf(sq + 1e-6f));

    float2 ss = block_sum2(x, x * x, tid, red);
    float mu = ss.x * (1.f / 256.f);
    float var = ss.y * (1.f / 256.f) - mu * mu;
    emb0[bs * 256 + tid] = (x - mu) * rsqrtf(var + 1e-3f);
}

// ---------------------------------------------------------------- K4: caps layer 0 (G=2 s-blocked, packed-f16 u)
__global__ void __launch_bounds__(256, 3) k_caps0(
        const float* __restrict__ embin, const u16* __restrict__ W0,
        const float* __restrict__ B0, float* __restrict__ embout) {
    int pb2 = blockIdx.x;
    int b = pb2 >> 8;
    int s0 = (pb2 & 255) << 1;            // handles s0, s0+1
    int tid = threadIdx.x;
    int o = tid >> 3;

    __shared__ __align__(16) u32 win2[2][I0 * 4];
    __shared__ float blog[2][I0 * 33];
    __shared__ __align__(16) u32 cpk[2][O0 * CPW];
    __shared__ float red[8];
    u16* cph0 = (u16*)cpk[0];
    u16* cph1 = (u16*)cpk[1];

    for (int idx = tid; idx < 2 * I0 * 4; idx += 256) {
        int g = idx >= I0 * 4;
        int lidx = idx - g * I0 * 4;
        int i = lidx >> 2, kk = lidx & 3;
        int sr = s0 + g + (i >> 5) - 1;
        float a = 0.f, bv = 0.f;
        if (sr >= 0 && sr < Sn) {
            const float* p = &embin[(b * Sn + sr) * 256 + (i & 31) * 8 + kk * 2];
            a = p[0]; bv = p[1];
        }
        win2[g][lidx] = pack2h(a, bv);
    }
    for (int i = tid; i < 2 * I0 * 33; i += 256) blog[0][i] = 0.f;  // covers both
    __syncthreads();

    // u_hat for both s, sharing W/B loads
    u32 u_pk0[48], u_pk1[48];
    {
        const uint4* Wv = (const uint4*)W0;
        const uint4* wl0 = (const uint4*)win2[0];
        const uint4* wl1 = (const uint4*)win2[1];
        #pragma unroll
        for (int ii = 0; ii < 48; ++ii) {
            int i0 = 2 * ii, i1 = 2 * ii + 1;
            uint4 wv0 = Wv[i0 * 256 + tid];
            uint4 wv1 = Wv[i1 * 256 + tid];
            float bb0 = B0[i0 * 256 + tid];
            float bb1 = B0[i1 * 256 + tid];
            uint4 wa0 = wl0[i0], wa1 = wl0[i1];
            float a0 = bb0, a1 = bb1;
            a0 = dot2(wv0.x, wa0.x, a0);
            a0 = dot2(wv0.y, wa0.y, a0);
            a0 = dot2(wv0.z, wa0.z, a0);
            a0 = dot2(wv0.w, wa0.w, a0);
            a1 = dot2(wv1.x, wa1.x, a1);
            a1 = dot2(wv1.y, wa1.y, a1);
            a1 = dot2(wv1.z, wa1.z, a1);
            a1 = dot2(wv1.w, wa1.w, a1);
            u_pk0[ii] = pack2h(a0, a1);
            uint4 wb0 = wl1[i0], wb1 = wl1[i1];
            a0 = bb0; a1 = bb1;
            a0 = dot2(wv0.x, wb0.x, a0);
            a0 = dot2(wv0.y, wb0.y, a0);
            a0 = dot2(wv0.z, wb0.z, a0);
            a0 = dot2(wv0.w, wb0.w, a0);
            a1 = dot2(wv1.x, wb1.x, a1);
            a1 = dot2(wv1.y, wb1.y, a1);
            a1 = dot2(wv1.z, wb1.z, a1);
            a1 = dot2(wv1.w, wb1.w, a1);
            u_pk1[ii] = pack2h(a0, a1);
        }
    }

    float vv0 = 0.f, vv1 = 0.f;
    for (int it = 0; it < 3; ++it) {
        if (tid < 192) {
            int i = tid >> 1, hf = tid & 1;
            int o0 = hf * 16;
            #pragma unroll
            for (int g = 0; g < 2; ++g) {
                float ex[16];
                float ssum = 0.f;
                #pragma unroll
                for (int j = 0; j < 16; ++j) {
                    ex[j] = __expf(blog[g][i * 33 + o0 + j]);
                    ssum += ex[j];
                }
                ssum += dpp_mov<0xB1>(ssum);
                float inv = __builtin_amdgcn_rcpf(ssum);
                u16* cc = g ? cph1 : cph0;
                #pragma unroll
                for (int j = 0; j < 16; ++j)
                    cc[(o0 + j) * (CPW * 2) + i] = f2h(ex[j] * inv);
            }
        }
        __syncthreads();
        {
            float sv0 = 0.f, sv1 = 0.f;
            const uint4* cr0 = (const uint4*)&cpk[0][o * CPW];
            const uint4* cr1 = (const uint4*)&cpk[1][o * CPW];
            #pragma unroll
            for (int q4 = 0; q4 < 12; ++q4) {
                uint4 c0 = cr0[q4], c1 = cr1[q4];
                sv0 = dot2(u_pk0[q4 * 4 + 0], c0.x, sv0);
                sv0 = dot2(u_pk0[q4 * 4 + 1], c0.y, sv0);
                sv0 = dot2(u_pk0[q4 * 4 + 2], c0.z, sv0);
                sv0 = dot2(u_pk0[q4 * 4 + 3], c0.w, sv0);
                sv1 = dot2(u_pk1[q4 * 4 + 0], c1.x, sv1);
                sv1 = dot2(u_pk1[q4 * 4 + 1], c1.y, sv1);
                sv1 = dot2(u_pk1[q4 * 4 + 2], c1.z, sv1);
                sv1 = dot2(u_pk1[q4 * 4 + 3], c1.w, sv1);
            }
            float sq0 = sum8(sv0 * sv0);
            float sq1 = sum8(sv1 * sv1);
            vv0 = sv0 * (sq0 / (1.f + sq0) * rsqrtf(sq0 + 1e-6f));
            vv1 = sv1 * (sq1 / (1.f + sq1) * rsqrtf(sq1 + 1e-6f));
        }
        if (it < 2) {
            u32 va = pack2h(vv0, vv0), vb = pack2h(vv1, vv1);
            #pragma unroll
            for (int ii = 0; ii < 48; ++ii) {
                u32 p0 = sum8h(h2u(u2h(u_pk0[ii]) * u2h(va)));
                u32 p1 = sum8h(h2u(u2h(u_pk1[ii]) * u2h(vb)));
                if ((tid & 7) == 0) {
                    h2 q0 = u2h(p0), q1 = u2h(p1);
                    blog[0][(2 * ii) * 33 + o]     += (float)q0[0];
                    blog[0][(2 * ii + 1) * 33 + o] += (float)q0[1];
                    blog[1][(2 * ii) * 33 + o]     += (float)q1[0];
                    blog[1][(2 * ii + 1) * 33 + o] += (float)q1[1];
                }
            }
            __syncthreads();
        }
    }

    // layernorm per s and write
    float2 ss = block_sum2(vv0, vv0 * vv0, tid, red);
    float mu = ss.x * (1.f / 256.f);
    float var = ss.y * (1.f / 256.f) - mu * mu;
    embout[(b * Sn + s0) * 256 + tid] = (vv0 - mu) * rsqrtf(var + 1e-3f);
    ss = block_sum2(vv1, vv1 * vv1, tid, red);
    mu = ss.x * (1.f / 256.f);
    var = ss.y * (1.f / 256.f) - mu * mu;
    embout[(b * Sn + s0 + 1) * 256 + tid] = (vv1 - mu) * rsqrtf(var + 1e-3f);
}

// ---------------------------------------------------------------- K5: caps layer 1 + epilogue (G=2)
__global__ void __launch_bounds__(256, 3) k_caps1(
        const float* __restrict__ embin, const u16* __restrict__ W1,
        const float* __restrict__ B1, float* __restrict__ outp) {
    int pb2 = blockIdx.x;
    int b = pb2 >> 8;
    int s0 = (pb2 & 255) << 1;
    int tid = threadIdx.x;
    int o = tid >> 3, d = tid & 7;
    bool valid = (o < O1);
    int oc = valid ? o : (O1 - 1);
    int ocd = oc * 8 + d;

    __shared__ __align__(16) u32 win2[2][I0 * 4];
    __shared__ float blog[2][I0 * 33];
    __shared__ __align__(16) u32 cpk[2][O1 * CPW];
    __shared__ float red[8];
    __shared__ float lenb[2][O1];
    __shared__ float mv2[4];
    u16* cph0 = (u16*)cpk[0];
    u16* cph1 = (u16*)cpk[1];

    for (int idx = tid; idx < 2 * I0 * 4; idx += 256) {
        int g = idx >= I0 * 4;
        int lidx = idx - g * I0 * 4;
        int i = lidx >> 2, kk = lidx & 3;
        int sr = s0 + g + (i >> 5) - 1;
        float a = 0.f, bv = 0.f;
        if (sr >= 0 && sr < Sn) {
            const float* p = &embin[(b * Sn + sr) * 256 + (i & 31) * 8 + kk * 2];
            a = p[0]; bv = p[1];
        }
        win2[g][lidx] = pack2h(a, bv);
    }
    for (int i = tid; i < 2 * I0 * 33; i += 256) blog[0][i] = 0.f;
    for (int i = tid; i < CPW; i += 256) { cpk[0][i] = 0; cpk[1][i] = 0; }  // class-0 rows
    __syncthreads();

    u32 u_pk0[48], u_pk1[48];
    {
        const uint4* Wv = (const uint4*)W1;
        const uint4* wl0 = (const uint4*)win2[0];
        const uint4* wl1 = (const uint4*)win2[1];
        #pragma unroll
        for (int ii = 0; ii < 48; ++ii) {
            int i0 = 2 * ii, i1 = 2 * ii + 1;
            uint4 wv0 = Wv[i0 * 248 + ocd];
            uint4 wv1 = Wv[i1 * 248 + ocd];
            float bb0 = B1[i0 * 248 + ocd];
            float bb1 = B1[i1 * 248 + ocd];
            uint4 wa0 = wl0[i0], wa1 = wl0[i1];
            float a0 = bb0, a1 = bb1;
            a0 = dot2(wv0.x, wa0.x, a0);
            a0 = dot2(wv0.y, wa0.y, a0);
            a0 = dot2(wv0.z, wa0.z, a0);
            a0 = dot2(wv0.w, wa0.w, a0);
            a1 = dot2(wv1.x, wa1.x, a1);
            a1 = dot2(wv1.y, wa1.y, a1);
            a1 = dot2(wv1.z, wa1.z, a1);
            a1 = dot2(wv1.w, wa1.w, a1);
            u_pk0[ii] = pack2h(a0, a1);
            uint4 wb0 = wl1[i0], wb1 = wl1[i1];
            a0 = bb0; a1 = bb1;
            a0 = dot2(wv0.x, wb0.x, a0);
            a0 = dot2(wv0.y, wb0.y, a0);
            a0 = dot2(wv0.z, wb0.z, a0);
            a0 = dot2(wv0.w, wb0.w, a0);
            a1 = dot2(wv1.x, wb1.x, a1);
            a1 = dot2(wv1.y, wb1.y, a1);
            a1 = dot2(wv1.z, wb1.z, a1);
            a1 = dot2(wv1.w, wb1.w, a1);
            u_pk1[ii] = pack2h(a0, a1);
        }
    }

    float vv0 = 0.f, vv1 = 0.f;
    for (int it = 0; it < 3; ++it) {
        if (tid < 192) {
            int i = tid >> 1, hf = tid & 1;
            int lo = hf ? 16 : 1;
            #pragma unroll
            for (int g = 0; g < 2; ++g) {
                float ex[15];
                float ssum = 0.f;
                #pragma unroll
                for (int j = 0; j < 15; ++j) {
                    ex[j] = __expf(blog[g][i * 33 + lo + j]);
                    ssum += ex[j];
                }
                ssum += dpp_mov<0xB1>(ssum);
                float inv = __builtin_amdgcn_rcpf(ssum);
                u16* cc = g ? cph1 : cph0;
                #pragma unroll
                for (int j = 0; j < 15; ++j)
                    cc[(lo + j) * (CPW * 2) + i] = f2h(ex[j] * inv);
            }
        }
        __syncthreads();
        {
            float sv0 = 0.f, sv1 = 0.f;
            const uint4* cr0 = (const uint4*)&cpk[0][oc * CPW];
            const uint4* cr1 = (const uint4*)&cpk[1][oc * CPW];
            #pragma unroll
            for (int q4 = 0; q4 < 12; ++q4) {
                uint4 c0 = cr0[q4], c1 = cr1[q4];
                sv0 = dot2(u_pk0[q4 * 4 + 0], c0.x, sv0);
                sv0 = dot2(u_pk0[q4 * 4 + 1], c0.y, sv0);
                sv0 = dot2(u_pk0[q4 * 4 + 2], c0.z, sv0);
                sv0 = dot2(u_pk0[q4 * 4 + 3], c0.w, sv0);
                sv1 = dot2(u_pk1[q4 * 4 + 0], c1.x, sv1);
                sv1 = dot2(u_pk1[q4 * 4 + 1], c1.y, sv1);
                sv1 = dot2(u_pk1[q4 * 4 + 2], c1.z, sv1);
                sv1 = dot2(u_pk1[q4 * 4 + 3], c1.w, sv1);
            }
            float sq0 = sum8(sv0 * sv0);
            float sq1 = sum8(sv1 * sv1);
            vv0 = sv0 * (sq0 / (1.f + sq0) * rsqrtf(sq0 + 1e-6f));
            vv1 = sv1 * (sq1 / (1.f + sq1) * rsqrtf(sq1 + 1e-6f));
            if (!valid) { vv0 = 0.f; vv1 = 0.f; }
        }
        if (it < 2) {
            u32 va = pack2h(vv0, vv0), vb = pack2h(vv1, vv1);
            #pragma unroll
            for (int ii = 0; ii < 48; ++ii) {
                u32 p0 = sum8h(h2u(u2h(u_pk0[ii]) * u2h(va)));
                u32 p1 = sum8h(h2u(u2h(u_pk1[ii]) * u2h(vb)));
                if ((tid & 7) == 0 && valid) {
                    h2 q0 = u2h(p0), q1 = u2h(p1);
                    blog[0][(2 * ii) * 33 + o]     += (float)q0[0];
                    blog[0][(2 * ii + 1) * 33 + o] += (float)q0[1];
                    blog[1][(2 * ii) * 33 + o]     += (float)q1[0];
                    blog[1][(2 * ii + 1) * 33 + o] += (float)q1[1];
                }
            }
            __syncthreads();
        }
    }

    // LN(248) + lengths per s
    float2 ss = block_sum2(vv0, vv0 * vv0, tid, red);
    float mu = ss.x * (1.f / 248.f);
    float var = ss.y * (1.f / 248.f) - mu * mu;
    float y0 = (vv0 - mu) * rsqrtf(var + 1e-3f);
    ss = block_sum2(vv1, vv1 * vv1, tid, red);
    mu = ss.x * (1.f / 248.f);
    var = ss.y * (1.f / 248.f) - mu * mu;
    float y1 = (vv1 - mu) * rsqrtf(var + 1e-3f);

    float sq0 = sum8(y0 * y0);
    float sq1 = sum8(y1 * y1);
    if (valid && (tid & 7) == 0) {
        lenb[0][o] = sqrtf(sq0 + 1e-6f);
        lenb[1][o] = sqrtf(sq1 + 1e-6f);
    }
    __syncthreads();

    if (tid < 2) {
        float s1 = 0.f, s2 = 0.f;
        for (int oo = 0; oo < O1; ++oo) { float t = lenb[tid][oo]; s1 += t; s2 += t * t; }
        float m2 = s1 / 31.f;
        mv2[tid * 2] = m2;
        mv2[tid * 2 + 1] = rsqrtf(s2 / 31.f - m2 * m2 + 1e-3f);
    }
    __syncthreads();
    if (tid < O1) {
        outp[(size_t)(b * Sn + s0) * O1 + tid] = (lenb[0][tid] - mv2[0]) * mv2[1];
        outp[(size_t)(b * Sn + s0 + 1) * O1 + tid] = (lenb[1][tid] - mv2[2]) * mv2[3];
    }
}

// ---------------------------------------------------------------- launch
extern "C" void kernel_launch(void* const* d_in, const int* in_sizes, int n_in,
                              void* d_out, int out_size, void* d_ws, size_t ws_size,
                              hipStream_t stream) {
    const float* inputs = (const float*)d_in[0];
    const float* c0w1 = (const float*)d_in[1];
    const float* c0b1 = (const float*)d_in[2];
    const float* c0w2 = (const float*)d_in[3];
    const float* c0b2 = (const float*)d_in[4];
    const float* c1w1 = (const float*)d_in[5];
    const float* c1b1 = (const float*)d_in[6];
    const float* c1w2 = (const float*)d_in[7];
    const float* c1b2 = (const float*)d_in[8];
    const float* pw   = (const float*)d_in[9];
    const float* pb   = (const float*)d_in[10];
    const float* ew1  = (const float*)d_in[11];
    const float* eb1  = (const float*)d_in[12];
    const float* ew2  = (const float*)d_in[13];
    const float* eb2  = (const float*)d_in[14];
    const float* W0   = (const float*)d_in[15];
    const float* B0   = (const float*)d_in[16];
    const float* W1   = (const float*)d_in[17];
    const float* B1   = (const float*)d_in[18];
    const int* lens = (const int*)d_in[19];

    char* ws = (char*)d_ws;
    u16*   x1    = (u16*)(ws);                       // 41,943,040 B
    u16*   x2    = (u16*)(ws + 41943040);            // 10,485,760 B (bf16)
    float* proj  = (float*)(ws + 52428800);          //    524,288 B
    float* emb0  = (float*)(ws + 52953088);          //  4,194,304 B
    float* emb1  = (float*)(ws + 57147392);          //  4,194,304 B
    u16*   W0h   = (u16*)(ws + 61341696);            //    393,216 B (f16)
    u16*   W1h   = (u16*)(ws + 61734912);            //    380,928 B (f16)
    u16*   wt    = (u16*)(ws + 62115840);            //    147,456 B
    float* biasi = (float*)(ws + 62263296);          //        512 B (end ~62.3 MB)

    k_prep<<<(NW0 + 255) / 256, 256, 0, stream>>>(
        W0, W1, c1w1, c1b1, c1w2, c1b2, W0h, W1h, wt, biasi);
    k_conv0<<<Bn * H1, 256, 0, stream>>>(
        inputs, c0w1, c0b1, c0w2, c0b2, lens, x1);
    k_conv1<<<640, 256, 0, stream>>>(x1, wt, biasi, lens, x2);
    k_proj<<<Bn * Sn, 256, 0, stream>>>(x2, pw, pb, proj);
    k_enc<<<Bn * Sn, 256, 0, stream>>>(proj, ew1, eb1, ew2, eb2, lens, emb0);
    k_caps0<<<Bn * Sn / 2, 256, 0, stream>>>(emb0, W0h, B0, emb1);
    k_caps1<<<Bn * Sn / 2, 256, 0, stream>>>(emb1, W1h, B1, (float*)d_out);
}